// Round 1
// baseline (387.223 us; speedup 1.0000x reference)
//
#include <hip/hip_runtime.h>
#include <cstdint>
#include <cstddef>

#define BATCH   16384
#define N_IN    128
#define CTX     128
#define HDIM    1024
#define NB      8
#define OUT_MULT 23          // 3*NB-1
#define NOUT    (N_IN * OUT_MULT)   // 2944
#define KCAT    (CTX + N_IN)        // 256

typedef __bf16 bf16x8 __attribute__((ext_vector_type(8)));
typedef float  f32x4  __attribute__((ext_vector_type(4)));

__device__ __forceinline__ uint16_t f2bf(float f) {
    union { float f; uint32_t u; } v; v.f = f;
    uint32_t u = v.u;
    u += 0x7FFFu + ((u >> 16) & 1u);   // RNE
    return (uint16_t)(u >> 16);
}
__device__ __forceinline__ float bf2f(uint16_t h) {
    union { uint32_t u; float f; } v; v.u = ((uint32_t)h) << 16;
    return v.f;
}

// async global->LDS, 16B per lane; LDS dest = wave-uniform base + lane*16
__device__ __forceinline__ void async_ld16(const void* g, const void* l) {
    __builtin_amdgcn_global_load_lds(
        (__attribute__((address_space(1))) void*)(uintptr_t)g,
        (__attribute__((address_space(3))) void*)(uint32_t)(uintptr_t)l,
        16, 0, 0);
}

// ---------------- weight / activation packing (masks computed analytically) --

__global__ void pack_xcat(const float* __restrict__ x, const float* __restrict__ ctx,
                          uint16_t* __restrict__ o) {
    int idx = blockIdx.x * 256 + threadIdx.x;          // BATCH*KCAT
    int b = idx >> 8, c = idx & 255;
    float v = (c < CTX) ? ctx[(b << 7) + c] : x[(b << 7) + (c - CTX)];
    o[idx] = f2bf(v);
}

__global__ void pack_wcat(const float* __restrict__ ctx_w, const float* __restrict__ w0,
                          uint16_t* __restrict__ o) {
    int idx = blockIdx.x * 256 + threadIdx.x;          // HDIM*KCAT
    int h = idx >> 8, c = idx & 255;
    float v;
    if (c < CTX) v = ctx_w[(h << 7) + c];
    else {
        int col = c - CTX;                              // mask0: (h%127) >= col
        v = ((h % (N_IN - 1)) >= col) ? w0[(h << 7) + col] : 0.0f;
    }
    o[idx] = f2bf(v);
}

__global__ void pack_w1(const float* __restrict__ w1, uint16_t* __restrict__ o) {
    int idx = blockIdx.x * 256 + threadIdx.x;          // HDIM*HDIM
    int h = idx >> 10, j = idx & 1023;                 // mask1: (h%127) >= (j%127)
    float v = ((h % (N_IN - 1)) >= (j % (N_IN - 1))) ? w1[idx] : 0.0f;
    o[idx] = f2bf(v);
}

__global__ void pack_w2(const float* __restrict__ w2, uint16_t* __restrict__ o) {
    int idx = blockIdx.x * 256 + threadIdx.x;          // NOUT*HDIM
    int oo = idx >> 10, h = idx & 1023;                // mask2: (oo/23) > (h%127)
    float v = ((oo / OUT_MULT) > (h % (N_IN - 1))) ? w2[idx] : 0.0f;
    o[idx] = f2bf(v);
}

// ---------------- bf16 GEMM, C = A(MxK) @ B(NxK)^T + bias  (m97 structure) ---
// EPI: 0 = relu + bf16 store, 1 = f32 store, 2 = bf16 store (no relu)

template<int EPI>
__global__ __launch_bounds__(256, 2) void gemm_bt(
    const uint16_t* __restrict__ A,
    const uint16_t* __restrict__ B,
    const float*    __restrict__ bias,
    void*           __restrict__ C,
    int M, int N, int K)
{
    __shared__ __align__(16) uint16_t sA[128 * 32];
    __shared__ __align__(16) uint16_t sB[128 * 32];

    const int tid   = threadIdx.x;
    const int wid   = tid >> 6;
    const int lane  = tid & 63;
    const int bm    = blockIdx.y << 7;
    const int bn    = blockIdx.x << 7;
    const int wm    = (wid & 1) << 6;
    const int wn    = (wid >> 1) << 6;
    const int lrow  = lane & 15;
    const int lquad = lane >> 4;

    const f32x4 vzero = {0.0f, 0.0f, 0.0f, 0.0f};
    f32x4 acc[4][4];
#pragma unroll
    for (int i = 0; i < 4; ++i)
#pragma unroll
        for (int j = 0; j < 4; ++j) acc[i][j] = vzero;

    // staging: 512 16B-chunks per tile; chunk c -> row c>>2, k-sub (c&3)*8
    const int c0 = (wid << 6) + lane;      // 0..255
    const int c1 = c0 + 256;               // 256..511
    const char* gA = (const char*)(A + (size_t)bm * K);
    const char* gB = (const char*)(B + (size_t)bn * K);
    const size_t ga0 = (size_t)(c0 >> 2) * K * 2 + (size_t)(c0 & 3) * 16;
    const size_t ga1 = (size_t)(c1 >> 2) * K * 2 + (size_t)(c1 & 3) * 16;
    const char* lA0 = (const char*)sA + (size_t)(wid << 6) * 16;   // wave-uniform
    const char* lA1 = lA0 + 256 * 16;
    const char* lB0 = (const char*)sB + (size_t)(wid << 6) * 16;
    const char* lB1 = lB0 + 256 * 16;

    const uint16_t* rA = sA + (wm + lrow) * 32 + lquad * 8;
    const uint16_t* rB = sB + (wn + lrow) * 32 + lquad * 8;

    for (int k0 = 0; k0 < K; k0 += 32) {
        __syncthreads();                    // LDS consumed by previous step
        const size_t kb = (size_t)k0 * 2;
        async_ld16(gA + ga0 + kb, lA0);
        async_ld16(gA + ga1 + kb, lA1);
        async_ld16(gB + ga0 + kb, lB0);
        async_ld16(gB + ga1 + kb, lB1);
        __syncthreads();                    // vmcnt(0) drained before barrier

        bf16x8 af[4], bfr[4];
#pragma unroll
        for (int i = 0; i < 4; ++i) af[i]  = *(const bf16x8*)(rA + i * 16 * 32);
#pragma unroll
        for (int j = 0; j < 4; ++j) bfr[j] = *(const bf16x8*)(rB + j * 16 * 32);
#pragma unroll
        for (int i = 0; i < 4; ++i)
#pragma unroll
            for (int j = 0; j < 4; ++j)
                acc[i][j] = __builtin_amdgcn_mfma_f32_16x16x32_bf16(
                                af[i], bfr[j], acc[i][j], 0, 0, 0);
    }

    // epilogue: C/D layout col=lane&15, row=(lane>>4)*4+reg
#pragma unroll
    for (int j = 0; j < 4; ++j) {
        const int col = bn + wn + j * 16 + lrow;
        const float bv = bias[col];
#pragma unroll
        for (int i = 0; i < 4; ++i) {
            const int row0 = bm + wm + i * 16 + (lquad << 2);
#pragma unroll
            for (int r = 0; r < 4; ++r) {
                float v = acc[i][j][r] + bv;
                if (EPI == 0) v = fmaxf(v, 0.0f);
                const size_t off = (size_t)(row0 + r) * N + col;
                if (EPI == 1) ((float*)C)[off] = v;
                else          ((uint16_t*)C)[off] = f2bf(v);
            }
        }
    }
}

// ---------------- rational-quadratic spline + logdet row-sum ----------------

__device__ __forceinline__ float softplusf(float v) {
    return fmaxf(v, 0.0f) + log1pf(expf(-fabsf(v)));
}

template<bool OUT_F32>
__global__ __launch_bounds__(128) void spline_kernel(
    const float* __restrict__ x,
    const void*  __restrict__ outbuf,
    float* __restrict__ y,
    float* __restrict__ ldsum)
{
    const int b = blockIdx.x;
    const int i = threadIdx.x;

    float p[OUT_MULT];
    if (OUT_F32) {
        const float* row = (const float*)outbuf + (size_t)b * NOUT + i * OUT_MULT;
#pragma unroll
        for (int k = 0; k < OUT_MULT; ++k) p[k] = row[k];
    } else {
        const uint16_t* row = (const uint16_t*)outbuf + (size_t)b * NOUT + i * OUT_MULT;
#pragma unroll
        for (int k = 0; k < OUT_MULT; ++k) p[k] = bf2f(row[k]);
    }

    const float TAILF = 3.0f;
    const float MIN_W = 0.001f, MIN_H = 0.001f, MIN_D = 0.001f;
    const float INV_SCALE = 1.0f / 724.0773439350246f;   // 1/sqrt(H*H/2)
    const float DPADF = logf(expf(1.0f - MIN_D) - 1.0f);

    const float xv = x[(size_t)b * N_IN + i];
    const float xc = fminf(fmaxf(xv, -TAILF), TAILF);

    float uw[NB], uh[NB];
#pragma unroll
    for (int k = 0; k < NB; ++k) { uw[k] = p[k] * INV_SCALE; uh[k] = p[NB + k] * INV_SCALE; }
    float mw = uw[0], mh = uh[0];
#pragma unroll
    for (int k = 1; k < NB; ++k) { mw = fmaxf(mw, uw[k]); mh = fmaxf(mh, uh[k]); }
    float ew[NB], eh[NB], sw = 0.0f, sh = 0.0f;
#pragma unroll
    for (int k = 0; k < NB; ++k) {
        ew[k] = expf(uw[k] - mw); sw += ew[k];
        eh[k] = expf(uh[k] - mh); sh += eh[k];
    }
    const float FACW = (1.0f - MIN_W * NB) / sw;
    const float FACH = (1.0f - MIN_H * NB) / sh;

    float cw[NB + 1], ch[NB + 1];
    cw[0] = -TAILF; ch[0] = -TAILF;
    float aw = 0.0f, ah = 0.0f;
#pragma unroll
    for (int k = 0; k < NB; ++k) {
        aw += MIN_W + FACW * ew[k];
        ah += MIN_H + FACH * eh[k];
        cw[k + 1] = (k == NB - 1) ? TAILF : 2.0f * TAILF * aw - TAILF;
        ch[k + 1] = (k == NB - 1) ? TAILF : 2.0f * TAILF * ah - TAILF;
    }

    float dd[NB + 1];
    dd[0]  = MIN_D + softplusf(DPADF);
    dd[NB] = dd[0];
#pragma unroll
    for (int k = 1; k < NB; ++k) dd[k] = MIN_D + softplusf(p[2 * NB + (k - 1)]);

    // bin select: largest k<=7 with xc >= cw[k]  (matches reference count-1 clip)
    float in_cw = cw[0], cw_n = cw[1], in_ch = ch[0], ch_n = ch[1];
    float d0 = dd[0], d1 = dd[1];
#pragma unroll
    for (int k = 1; k < NB; ++k) {
        const bool ge = (xc >= cw[k]);
        in_cw = ge ? cw[k]     : in_cw;
        cw_n  = ge ? cw[k + 1] : cw_n;
        in_ch = ge ? ch[k]     : in_ch;
        ch_n  = ge ? ch[k + 1] : ch_n;
        d0    = ge ? dd[k]     : d0;
        d1    = ge ? dd[k + 1] : d1;
    }
    const float in_w  = cw_n - in_cw;
    const float in_h  = ch_n - in_ch;
    const float delta = in_h / in_w;
    const float theta = (xc - in_cw) / in_w;
    const float omt   = 1.0f - theta;
    const float t1m   = theta * omt;
    const float denom = delta + (d0 + d1 - 2.0f * delta) * t1m;
    const float num   = in_h * (delta * theta * theta + d0 * t1m);
    float yv = in_ch + num / denom;
    float ld = 2.0f * logf(delta)
             + logf(d1 * theta * theta + 2.0f * delta * t1m + d0 * omt * omt)
             - 2.0f * logf(denom);
    const bool inside = fabsf(xv) <= TAILF;
    yv = inside ? yv : xv;
    ld = inside ? ld : 0.0f;
    y[(size_t)b * N_IN + i] = yv;

    float v = ld;
#pragma unroll
    for (int o = 32; o > 0; o >>= 1) v += __shfl_down(v, o, 64);
    __shared__ float sred[2];
    if ((i & 63) == 0) sred[i >> 6] = v;
    __syncthreads();
    if (i == 0) ldsum[b] = sred[0] + sred[1];
}

// ---------------- host orchestration ----------------------------------------

extern "C" void kernel_launch(void* const* d_in, const int* in_sizes, int n_in,
                              void* d_out, int out_size, void* d_ws, size_t ws_size,
                              hipStream_t stream)
{
    const float* x     = (const float*)d_in[0];
    const float* ctx   = (const float*)d_in[1];
    const float* ctx_w = (const float*)d_in[2];
    const float* w0    = (const float*)d_in[3];
    const float* b0    = (const float*)d_in[4];
    const float* w1    = (const float*)d_in[5];
    const float* b1    = (const float*)d_in[6];
    const float* w2    = (const float*)d_in[7];
    const float* b2    = (const float*)d_in[8];
    // d_in[9..11] = masks: unused (computed analytically from indices)

    char* ws = (char*)d_ws;
    const size_t XCAT_B = (size_t)BATCH * KCAT * 2;   //   8 MB
    const size_t H1_B   = (size_t)BATCH * HDIM * 2;   //  32 MB
    const size_t H2_B   = H1_B;                       //  32 MB
    const size_t WCAT_B = (size_t)HDIM * KCAT * 2;
    const size_t W1_B   = (size_t)HDIM * HDIM * 2;
    const size_t W2_B   = (size_t)NOUT * HDIM * 2;
    const size_t OUTF_B = (size_t)BATCH * NOUT * 4;   // 193 MB
    const size_t OUTH_B = (size_t)BATCH * NOUT * 2;   //  96 MB

    const size_t need_f32 = OUTF_B + H2_B + WCAT_B + W1_B + W2_B;   // ~235 MB
    const bool   f32out   = (ws_size >= need_f32);
    const size_t outreg   = f32out ? OUTF_B : OUTH_B;  // both > XCAT_B+H1_B (42MB)

    // out region [0,outreg) aliases xcat+h1 (dead before GEMM3 writes out)
    uint16_t* xcat = (uint16_t*)(ws);
    uint16_t* h1   = (uint16_t*)(ws + XCAT_B);
    void*     outb = (void*)(ws);
    uint16_t* h2   = (uint16_t*)(ws + outreg);
    uint16_t* wcat = (uint16_t*)(ws + outreg + H2_B);
    uint16_t* w1m  = (uint16_t*)(ws + outreg + H2_B + WCAT_B);
    uint16_t* w2m  = (uint16_t*)(ws + outreg + H2_B + WCAT_B + W1_B);

    float* yout  = (float*)d_out;
    float* ldout = yout + (size_t)BATCH * N_IN;

    pack_xcat<<<(BATCH * KCAT) / 256, 256, 0, stream>>>(x, ctx, xcat);
    pack_wcat<<<(HDIM * KCAT) / 256, 256, 0, stream>>>(ctx_w, w0, wcat);
    pack_w1  <<<(HDIM * HDIM) / 256, 256, 0, stream>>>(w1, w1m);
    pack_w2  <<<(NOUT * HDIM) / 256, 256, 0, stream>>>(w2, w2m);

    const dim3 blk(256);
    gemm_bt<0><<<dim3(HDIM / 128, BATCH / 128), blk, 0, stream>>>(
        xcat, wcat, b0, h1, BATCH, HDIM, KCAT);
    gemm_bt<0><<<dim3(HDIM / 128, BATCH / 128), blk, 0, stream>>>(
        h1, w1m, b1, h2, BATCH, HDIM, HDIM);

    if (f32out) {
        gemm_bt<1><<<dim3(NOUT / 128, BATCH / 128), blk, 0, stream>>>(
            h2, w2m, b2, outb, BATCH, NOUT, HDIM);
        spline_kernel<true><<<BATCH, 128, 0, stream>>>(x, outb, yout, ldout);
    } else {
        gemm_bt<2><<<dim3(NOUT / 128, BATCH / 128), blk, 0, stream>>>(
            h2, w2m, b2, outb, BATCH, NOUT, HDIM);
        spline_kernel<false><<<BATCH, 128, 0, stream>>>(x, outb, yout, ldout);
    }
}

// Round 2
// 352.144 us; speedup vs baseline: 1.0996x; 1.0996x over previous
//
#include <hip/hip_runtime.h>
#include <cstdint>
#include <cstddef>

#define BATCH   16384
#define N_IN    128
#define CTX     128
#define HDIM    1024
#define NB      8
#define OUT_MULT 23          // 3*NB-1
#define NOUT    (N_IN * OUT_MULT)   // 2944
#define KCAT    (CTX + N_IN)        // 256

typedef __bf16 bf16x8 __attribute__((ext_vector_type(8)));
typedef float  f32x4  __attribute__((ext_vector_type(4)));

__device__ __forceinline__ uint16_t f2bf(float f) {
    union { float f; uint32_t u; } v; v.f = f;
    uint32_t u = v.u;
    u += 0x7FFFu + ((u >> 16) & 1u);   // RNE
    return (uint16_t)(u >> 16);
}
__device__ __forceinline__ float bf2f(uint16_t h) {
    union { uint32_t u; float f; } v; v.u = ((uint32_t)h) << 16;
    return v.f;
}

// async global->LDS, 16B per lane; LDS dest = wave-uniform base + lane*16
__device__ __forceinline__ void async_ld16(const void* g, const void* l) {
    __builtin_amdgcn_global_load_lds(
        (__attribute__((address_space(1))) void*)(uintptr_t)g,
        (__attribute__((address_space(3))) void*)(uint32_t)(uintptr_t)l,
        16, 0, 0);
}

// ---------------- weight / activation packing (masks computed analytically) --

__global__ void pack_xcat(const float* __restrict__ x, const float* __restrict__ ctx,
                          uint16_t* __restrict__ o) {
    int idx = blockIdx.x * 256 + threadIdx.x;          // BATCH*KCAT
    int b = idx >> 8, c = idx & 255;
    float v = (c < CTX) ? ctx[(b << 7) + c] : x[(b << 7) + (c - CTX)];
    o[idx] = f2bf(v);
}

__global__ void pack_wcat(const float* __restrict__ ctx_w, const float* __restrict__ w0,
                          uint16_t* __restrict__ o) {
    int idx = blockIdx.x * 256 + threadIdx.x;          // HDIM*KCAT
    int h = idx >> 8, c = idx & 255;
    float v;
    if (c < CTX) v = ctx_w[(h << 7) + c];
    else {
        int col = c - CTX;                              // mask0: (h%127) >= col
        v = ((h % (N_IN - 1)) >= col) ? w0[(h << 7) + col] : 0.0f;
    }
    o[idx] = f2bf(v);
}

__global__ void pack_w1(const float* __restrict__ w1, uint16_t* __restrict__ o) {
    int idx = blockIdx.x * 256 + threadIdx.x;          // HDIM*HDIM
    int h = idx >> 10, j = idx & 1023;                 // mask1: (h%127) >= (j%127)
    float v = ((h % (N_IN - 1)) >= (j % (N_IN - 1))) ? w1[idx] : 0.0f;
    o[idx] = f2bf(v);
}

__global__ void pack_w2(const float* __restrict__ w2, uint16_t* __restrict__ o) {
    int idx = blockIdx.x * 256 + threadIdx.x;          // NOUT*HDIM
    int oo = idx >> 10, h = idx & 1023;                // mask2: (oo/23) > (h%127)
    float v = ((oo / OUT_MULT) > (h % (N_IN - 1))) ? w2[idx] : 0.0f;
    o[idx] = f2bf(v);
}

// ---------------- bf16 GEMM, C = A(MxK) @ B(NxK)^T + bias  (m97 structure) ---
// EPI: 0 = relu + bf16 store, 2 = bf16 store (no relu)
// 1D grid of MT*NT blocks, swizzled so that within each 64-M-tile group the
// M-tile index is the fastest-varying. With round-robin wg->XCD dispatch,
// XCD c then consistently touches A-tiles == c (mod 8): 8 tiles x 256KB = 2MB
// per XCD, L2-resident across all NT sweeps of B.

template<int EPI>
__global__ __launch_bounds__(256, 2) void gemm_bt(
    const uint16_t* __restrict__ A,
    const uint16_t* __restrict__ B,
    const float*    __restrict__ bias,
    void*           __restrict__ C,
    int N, int K, int NT)
{
    __shared__ __align__(16) uint16_t sA[128 * 32];
    __shared__ __align__(16) uint16_t sB[128 * 32];

    // swizzle: group of 64 M-tiles, M fastest within group
    const int GM    = 64;
    const int per   = GM * NT;
    const int id    = blockIdx.x;
    const int grp   = id / per;
    const int rem   = id - grp * per;
    const int mt    = grp * GM + (rem & (GM - 1));
    const int nt    = rem >> 6;            // rem / GM
    const int bm    = mt << 7;
    const int bn    = nt << 7;

    const int tid   = threadIdx.x;
    const int wid   = tid >> 6;
    const int lane  = tid & 63;
    const int wm    = (wid & 1) << 6;
    const int wn    = (wid >> 1) << 6;
    const int lrow  = lane & 15;
    const int lquad = lane >> 4;

    const f32x4 vzero = {0.0f, 0.0f, 0.0f, 0.0f};
    f32x4 acc[4][4];
#pragma unroll
    for (int i = 0; i < 4; ++i)
#pragma unroll
        for (int j = 0; j < 4; ++j) acc[i][j] = vzero;

    // staging: 512 16B-chunks per tile; chunk c -> row c>>2, k-sub (c&3)*8
    const int c0 = (wid << 6) + lane;      // 0..255
    const int c1 = c0 + 256;               // 256..511
    const char* gA = (const char*)(A + (size_t)bm * K);
    const char* gB = (const char*)(B + (size_t)bn * K);
    const size_t ga0 = (size_t)(c0 >> 2) * K * 2 + (size_t)(c0 & 3) * 16;
    const size_t ga1 = (size_t)(c1 >> 2) * K * 2 + (size_t)(c1 & 3) * 16;
    const char* lA0 = (const char*)sA + (size_t)(wid << 6) * 16;   // wave-uniform
    const char* lA1 = lA0 + 256 * 16;
    const char* lB0 = (const char*)sB + (size_t)(wid << 6) * 16;
    const char* lB1 = lB0 + 256 * 16;

    const uint16_t* rA = sA + (wm + lrow) * 32 + lquad * 8;
    const uint16_t* rB = sB + (wn + lrow) * 32 + lquad * 8;

    for (int k0 = 0; k0 < K; k0 += 32) {
        __syncthreads();                    // LDS consumed by previous step
        const size_t kb = (size_t)k0 * 2;
        async_ld16(gA + ga0 + kb, lA0);
        async_ld16(gA + ga1 + kb, lA1);
        async_ld16(gB + ga0 + kb, lB0);
        async_ld16(gB + ga1 + kb, lB1);
        __syncthreads();                    // vmcnt(0) drained before barrier

        bf16x8 af[4], bfr[4];
#pragma unroll
        for (int i = 0; i < 4; ++i) af[i]  = *(const bf16x8*)(rA + i * 16 * 32);
#pragma unroll
        for (int j = 0; j < 4; ++j) bfr[j] = *(const bf16x8*)(rB + j * 16 * 32);
#pragma unroll
        for (int i = 0; i < 4; ++i)
#pragma unroll
            for (int j = 0; j < 4; ++j)
                acc[i][j] = __builtin_amdgcn_mfma_f32_16x16x32_bf16(
                                af[i], bfr[j], acc[i][j], 0, 0, 0);
    }

    // epilogue: C/D layout col=lane&15, row=(lane>>4)*4+reg
#pragma unroll
    for (int j = 0; j < 4; ++j) {
        const int col = bn + wn + j * 16 + lrow;
        const float bv = bias[col];
#pragma unroll
        for (int i = 0; i < 4; ++i) {
            const int row0 = bm + wm + i * 16 + (lquad << 2);
#pragma unroll
            for (int r = 0; r < 4; ++r) {
                float v = acc[i][j][r] + bv;
                if (EPI == 0) v = fmaxf(v, 0.0f);
                const size_t off = (size_t)(row0 + r) * N + col;
                ((uint16_t*)C)[off] = f2bf(v);
            }
        }
    }
}

// ---------------- rational-quadratic spline + logdet row-sum ----------------
// 256 threads / block, 2 batch rows per block; out rows staged via LDS uint4.

__device__ __forceinline__ float softplusf(float v) {
    return fmaxf(v, 0.0f) + log1pf(expf(-fabsf(v)));
}

__global__ __launch_bounds__(256) void spline_kernel(
    const float*    __restrict__ x,
    const uint16_t* __restrict__ outbuf,
    float* __restrict__ y,
    float* __restrict__ ldsum)
{
    const int b0  = blockIdx.x << 1;
    const int tid = threadIdx.x;
    const int r   = tid >> 7;          // row within block
    const int i   = tid & 127;         // spline element

    __shared__ uint4 sbuf[736];        // 2 * NOUT bf16 = 11776 B
    {
        const uint4* g = (const uint4*)(outbuf + (size_t)b0 * NOUT);
#pragma unroll
        for (int k = 0; k < 3; ++k) {
            int c = tid + k * 256;
            if (c < 736) sbuf[c] = g[c];
        }
    }
    __syncthreads();

    const uint16_t* srow = (const uint16_t*)sbuf + r * NOUT + i * OUT_MULT;
    float p[OUT_MULT];
#pragma unroll
    for (int k = 0; k < OUT_MULT; ++k) p[k] = bf2f(srow[k]);

    const float TAILF = 3.0f;
    const float MIN_W = 0.001f, MIN_H = 0.001f, MIN_D = 0.001f;
    const float INV_SCALE = 1.0f / 724.0773439350246f;   // 1/sqrt(H*H/2)
    const float DPADF = logf(expf(1.0f - MIN_D) - 1.0f);

    const float xv = x[(size_t)(b0 + r) * N_IN + i];
    const float xc = fminf(fmaxf(xv, -TAILF), TAILF);

    float uw[NB], uh[NB];
#pragma unroll
    for (int k = 0; k < NB; ++k) { uw[k] = p[k] * INV_SCALE; uh[k] = p[NB + k] * INV_SCALE; }
    float mw = uw[0], mh = uh[0];
#pragma unroll
    for (int k = 1; k < NB; ++k) { mw = fmaxf(mw, uw[k]); mh = fmaxf(mh, uh[k]); }
    float ew[NB], eh[NB], sw = 0.0f, sh = 0.0f;
#pragma unroll
    for (int k = 0; k < NB; ++k) {
        ew[k] = expf(uw[k] - mw); sw += ew[k];
        eh[k] = expf(uh[k] - mh); sh += eh[k];
    }
    const float FACW = (1.0f - MIN_W * NB) / sw;
    const float FACH = (1.0f - MIN_H * NB) / sh;

    float cw[NB + 1], ch[NB + 1];
    cw[0] = -TAILF; ch[0] = -TAILF;
    float aw = 0.0f, ah = 0.0f;
#pragma unroll
    for (int k = 0; k < NB; ++k) {
        aw += MIN_W + FACW * ew[k];
        ah += MIN_H + FACH * eh[k];
        cw[k + 1] = (k == NB - 1) ? TAILF : 2.0f * TAILF * aw - TAILF;
        ch[k + 1] = (k == NB - 1) ? TAILF : 2.0f * TAILF * ah - TAILF;
    }

    float dd[NB + 1];
    dd[0]  = MIN_D + softplusf(DPADF);
    dd[NB] = dd[0];
#pragma unroll
    for (int k = 1; k < NB; ++k) dd[k] = MIN_D + softplusf(p[2 * NB + (k - 1)]);

    // bin select: largest k<=7 with xc >= cw[k]
    float in_cw = cw[0], cw_n = cw[1], in_ch = ch[0], ch_n = ch[1];
    float d0 = dd[0], d1 = dd[1];
#pragma unroll
    for (int k = 1; k < NB; ++k) {
        const bool ge = (xc >= cw[k]);
        in_cw = ge ? cw[k]     : in_cw;
        cw_n  = ge ? cw[k + 1] : cw_n;
        in_ch = ge ? ch[k]     : in_ch;
        ch_n  = ge ? ch[k + 1] : ch_n;
        d0    = ge ? dd[k]     : d0;
        d1    = ge ? dd[k + 1] : d1;
    }
    const float in_w  = cw_n - in_cw;
    const float in_h  = ch_n - in_ch;
    const float delta = in_h / in_w;
    const float theta = (xc - in_cw) / in_w;
    const float omt   = 1.0f - theta;
    const float t1m   = theta * omt;
    const float denom = delta + (d0 + d1 - 2.0f * delta) * t1m;
    const float num   = in_h * (delta * theta * theta + d0 * t1m);
    float yv = in_ch + num / denom;
    float ld = 2.0f * logf(delta)
             + logf(d1 * theta * theta + 2.0f * delta * t1m + d0 * omt * omt)
             - 2.0f * logf(denom);
    const bool inside = fabsf(xv) <= TAILF;
    yv = inside ? yv : xv;
    ld = inside ? ld : 0.0f;
    y[(size_t)(b0 + r) * N_IN + i] = yv;

    float v = ld;
#pragma unroll
    for (int o = 32; o > 0; o >>= 1) v += __shfl_down(v, o, 64);
    __shared__ float sred[4];
    const int w = tid >> 6;
    if ((tid & 63) == 0) sred[w] = v;
    __syncthreads();
    if (tid == 0)   ldsum[b0]     = sred[0] + sred[1];
    if (tid == 128) ldsum[b0 + 1] = sred[2] + sred[3];
}

// ---------------- host orchestration ----------------------------------------

extern "C" void kernel_launch(void* const* d_in, const int* in_sizes, int n_in,
                              void* d_out, int out_size, void* d_ws, size_t ws_size,
                              hipStream_t stream)
{
    const float* x     = (const float*)d_in[0];
    const float* ctx   = (const float*)d_in[1];
    const float* ctx_w = (const float*)d_in[2];
    const float* w0    = (const float*)d_in[3];
    const float* b0    = (const float*)d_in[4];
    const float* w1    = (const float*)d_in[5];
    const float* b1    = (const float*)d_in[6];
    const float* w2    = (const float*)d_in[7];
    const float* b2    = (const float*)d_in[8];
    // d_in[9..11] = masks: unused (computed analytically from indices)

    char* ws = (char*)d_ws;
    const size_t XCAT_B = (size_t)BATCH * KCAT * 2;   //   8 MB
    const size_t H1_B   = (size_t)BATCH * HDIM * 2;   //  32 MB
    const size_t H2_B   = H1_B;                       //  32 MB
    const size_t WCAT_B = (size_t)HDIM * KCAT * 2;
    const size_t W1_B   = (size_t)HDIM * HDIM * 2;
    const size_t OUTH_B = (size_t)BATCH * NOUT * 2;   //  96 MB

    // out region [0,OUTH_B) aliases xcat+h1 (both dead before GEMM3 writes out)
    uint16_t* xcat = (uint16_t*)(ws);
    uint16_t* h1   = (uint16_t*)(ws + XCAT_B);
    uint16_t* outb = (uint16_t*)(ws);
    uint16_t* h2   = (uint16_t*)(ws + OUTH_B);
    uint16_t* wcat = (uint16_t*)(ws + OUTH_B + H2_B);
    uint16_t* w1m  = (uint16_t*)(ws + OUTH_B + H2_B + WCAT_B);
    uint16_t* w2m  = (uint16_t*)(ws + OUTH_B + H2_B + WCAT_B + W1_B);

    float* yout  = (float*)d_out;
    float* ldout = yout + (size_t)BATCH * N_IN;

    pack_xcat<<<(BATCH * KCAT) / 256, 256, 0, stream>>>(x, ctx, xcat);
    pack_wcat<<<(HDIM * KCAT) / 256, 256, 0, stream>>>(ctx_w, w0, wcat);
    pack_w1  <<<(HDIM * HDIM) / 256, 256, 0, stream>>>(w1, w1m);
    pack_w2  <<<(NOUT * HDIM) / 256, 256, 0, stream>>>(w2, w2m);

    const dim3 blk(256);
    // MT = 128 for all three GEMMs; 1D swizzled grid = MT * NT
    gemm_bt<0><<<dim3(128 * (HDIM / 128)), blk, 0, stream>>>(
        xcat, wcat, b0, h1, HDIM, KCAT, HDIM / 128);
    gemm_bt<0><<<dim3(128 * (HDIM / 128)), blk, 0, stream>>>(
        h1, w1m, b1, h2, HDIM, HDIM, HDIM / 128);
    gemm_bt<2><<<dim3(128 * (NOUT / 128)), blk, 0, stream>>>(
        h2, w2m, b2, outb, NOUT, HDIM, NOUT / 128);

    spline_kernel<<<BATCH / 2, 256, 0, stream>>>(x, outb, yout, ldout);
}

// Round 3
// 266.406 us; speedup vs baseline: 1.4535x; 1.3218x over previous
//
#include <hip/hip_runtime.h>
#include <cstdint>
#include <cstddef>

#define BATCH   16384
#define N_IN    128
#define CTX     128
#define HDIM    1024
#define NB      8
#define OUT_MULT 23          // 3*NB-1
#define NOUT    (N_IN * OUT_MULT)   // 2944
#define KCAT    (CTX + N_IN)        // 256

typedef __bf16 bf16x8 __attribute__((ext_vector_type(8)));
typedef float  f32x4  __attribute__((ext_vector_type(4)));

__device__ __forceinline__ uint16_t f2bf(float f) {
    union { float f; uint32_t u; } v; v.f = f;
    uint32_t u = v.u;
    u += 0x7FFFu + ((u >> 16) & 1u);   // RNE
    return (uint16_t)(u >> 16);
}
__device__ __forceinline__ float bf2f(uint16_t h) {
    union { uint32_t u; float f; } v; v.u = ((uint32_t)h) << 16;
    return v.f;
}

// ---- degree-sorted permutation of the hidden dim ---------------------------
// deg(h) = h % 127; stable sort by deg. count(d) = 9 for d<8, 8 for d>=8.
// kpref(d) = #{h : deg(h) < d}; position p -> (d, occurrence j) -> h = d+127*j
__device__ __forceinline__ int kpref_dev(int d) {
    return (d <= 8) ? 9 * d : 72 + 8 * (d - 8);
}
__device__ __forceinline__ int dpos_dev(int p) {
    return (p < 72) ? (p / 9) : (8 + ((p - 72) >> 3));
}
__device__ __forceinline__ int h_of(int p) {
    if (p < 72) { int d = p / 9, j = p - 9 * d; return d + 127 * j; }
    int q = p - 72; int d = 8 + (q >> 3); int j = q & 7; return d + 127 * j;
}

// async global->LDS, 16B per lane; LDS dest = wave-uniform base + lane*16
__device__ __forceinline__ void async_ld16(const void* g, const void* l) {
    __builtin_amdgcn_global_load_lds(
        (__attribute__((address_space(1))) void*)(uintptr_t)g,
        (__attribute__((address_space(3))) void*)(uint32_t)(uintptr_t)l,
        16, 0, 0);
}

// ---------------- packing (masks analytic; hidden dim degree-sorted) --------

__global__ void pack_xcat(const float* __restrict__ x, const float* __restrict__ ctx,
                          uint16_t* __restrict__ o) {
    int idx = blockIdx.x * 256 + threadIdx.x;          // BATCH*KCAT
    int b = idx >> 8, c = idx & 255;
    float v = (c < CTX) ? ctx[(b << 7) + c] : x[(b << 7) + (c - CTX)];
    o[idx] = f2bf(v);
}

__global__ void pack_wcat(const float* __restrict__ ctx_w, const float* __restrict__ w0,
                          uint16_t* __restrict__ o) {
    int idx = blockIdx.x * 256 + threadIdx.x;          // HDIM*KCAT (rows sorted)
    int p = idx >> 8, c = idx & 255;
    int h = h_of(p);
    float v;
    if (c < CTX) v = ctx_w[(h << 7) + c];
    else {
        int col = c - CTX;                              // mask0: deg(h) >= col
        v = (dpos_dev(p) >= col) ? w0[(h << 7) + col] : 0.0f;
    }
    o[idx] = f2bf(v);
}

__global__ void pack_w1(const float* __restrict__ w1, uint16_t* __restrict__ o) {
    int idx = blockIdx.x * 256 + threadIdx.x;          // HDIM*HDIM (both sorted)
    int po = idx >> 10, pi = idx & 1023;
    float v = (dpos_dev(po) >= dpos_dev(pi))
            ? w1[h_of(po) * HDIM + h_of(pi)] : 0.0f;
    o[idx] = f2bf(v);
}

__global__ void pack_w2(const float* __restrict__ w2, uint16_t* __restrict__ o) {
    int idx = blockIdx.x * 256 + threadIdx.x;          // NOUT*HDIM (K sorted)
    int oo = idx >> 10, pi = idx & 1023;
    float v = ((oo / OUT_MULT) > dpos_dev(pi))         // mask2: g > deg
            ? w2[oo * HDIM + h_of(pi)] : 0.0f;
    o[idx] = f2bf(v);
}

__global__ void pack_bias(const float* __restrict__ b0, const float* __restrict__ b1,
                          float* __restrict__ b0p, float* __restrict__ b1p) {
    int p = blockIdx.x * 256 + threadIdx.x;            // HDIM
    int h = h_of(p);
    b0p[p] = b0[h];
    b1p[p] = b1[h];
}

// ---------------- bf16 GEMM, C = A(MxK) @ B(NxK)^T + bias  (m97 structure) ---
// EPI: 0 = relu + bf16 store, 2 = bf16 store (no relu)
// MODE selects the per-N-tile K prefix (degree-sorted masks => zero tail):
//   0: GEMM1  K_eff = 128 + dmax + 1
//   1: GEMM2  K_eff = kpref(dmax+1)
//   2: GEMM3  K_eff = kpref(gmax),  gmax = (bn+127)/23
// Skipped K region has exactly-zero B => result bit-identical to full K.

template<int EPI, int MODE>
__global__ __launch_bounds__(256, 2) void gemm_bt(
    const uint16_t* __restrict__ A,
    const uint16_t* __restrict__ B,
    const float*    __restrict__ bias,
    void*           __restrict__ C,
    int N, int K, int NT)
{
    __shared__ __align__(16) uint16_t sA[128 * 32];
    __shared__ __align__(16) uint16_t sB[128 * 32];

    // swizzle: group of 64 M-tiles, M fastest within group (XCD L2 locality)
    const int GM    = 64;
    const int per   = GM * NT;
    const int id    = blockIdx.x;
    const int grp   = id / per;
    const int rem   = id - grp * per;
    const int mt    = grp * GM + (rem & (GM - 1));
    const int nt    = rem >> 6;
    const int bm    = mt << 7;
    const int bn    = nt << 7;

    int K_eff;
    if (MODE == 0)      { int dmax = dpos_dev(bn + 127); K_eff = 128 + dmax + 1; }
    else if (MODE == 1) { int dmax = dpos_dev(bn + 127); K_eff = kpref_dev(dmax + 1); }
    else                { int gmax = (bn + 127) / OUT_MULT; K_eff = kpref_dev(gmax); }
    K_eff = min(K, (K_eff + 31) & ~31);

    const int tid   = threadIdx.x;
    const int wid   = tid >> 6;
    const int lane  = tid & 63;
    const int wm    = (wid & 1) << 6;
    const int wn    = (wid >> 1) << 6;
    const int lrow  = lane & 15;
    const int lquad = lane >> 4;

    const f32x4 vzero = {0.0f, 0.0f, 0.0f, 0.0f};
    f32x4 acc[4][4];
#pragma unroll
    for (int i = 0; i < 4; ++i)
#pragma unroll
        for (int j = 0; j < 4; ++j) acc[i][j] = vzero;

    // staging: 512 16B-chunks per tile; chunk c -> row c>>2, k-sub (c&3)*8
    const int c0 = (wid << 6) + lane;      // 0..255
    const int c1 = c0 + 256;               // 256..511
    const char* gA = (const char*)(A + (size_t)bm * K);
    const char* gB = (const char*)(B + (size_t)bn * K);
    const size_t ga0 = (size_t)(c0 >> 2) * K * 2 + (size_t)(c0 & 3) * 16;
    const size_t ga1 = (size_t)(c1 >> 2) * K * 2 + (size_t)(c1 & 3) * 16;
    const char* lA0 = (const char*)sA + (size_t)(wid << 6) * 16;   // wave-uniform
    const char* lA1 = lA0 + 256 * 16;
    const char* lB0 = (const char*)sB + (size_t)(wid << 6) * 16;
    const char* lB1 = lB0 + 256 * 16;

    const uint16_t* rA = sA + (wm + lrow) * 32 + lquad * 8;
    const uint16_t* rB = sB + (wn + lrow) * 32 + lquad * 8;

    for (int k0 = 0; k0 < K_eff; k0 += 32) {
        __syncthreads();                    // LDS consumed by previous step
        const size_t kb = (size_t)k0 * 2;
        async_ld16(gA + ga0 + kb, lA0);
        async_ld16(gA + ga1 + kb, lA1);
        async_ld16(gB + ga0 + kb, lB0);
        async_ld16(gB + ga1 + kb, lB1);
        __syncthreads();                    // vmcnt(0) drained before barrier

        bf16x8 af[4], bfr[4];
#pragma unroll
        for (int i = 0; i < 4; ++i) af[i]  = *(const bf16x8*)(rA + i * 16 * 32);
#pragma unroll
        for (int j = 0; j < 4; ++j) bfr[j] = *(const bf16x8*)(rB + j * 16 * 32);
#pragma unroll
        for (int i = 0; i < 4; ++i)
#pragma unroll
            for (int j = 0; j < 4; ++j)
                acc[i][j] = __builtin_amdgcn_mfma_f32_16x16x32_bf16(
                                af[i], bfr[j], acc[i][j], 0, 0, 0);
    }

    // epilogue: C/D layout col=lane&15, row=(lane>>4)*4+reg
#pragma unroll
    for (int j = 0; j < 4; ++j) {
        const int col = bn + wn + j * 16 + lrow;
        const float bv = bias[col];
#pragma unroll
        for (int i = 0; i < 4; ++i) {
            const int row0 = bm + wm + i * 16 + (lquad << 2);
#pragma unroll
            for (int r = 0; r < 4; ++r) {
                float v = acc[i][j][r] + bv;
                if (EPI == 0) v = fmaxf(v, 0.0f);
                const size_t off = (size_t)(row0 + r) * N + col;
                ((uint16_t*)C)[off] = f2bf(v);
            }
        }
    }
}

// ---------------- rational-quadratic spline + logdet row-sum ----------------
// 256 threads / block, 2 batch rows per block; HW transcendentals.

__device__ __forceinline__ float frcp(float v) { return __builtin_amdgcn_rcpf(v); }
__device__ __forceinline__ float softplusf(float v) {
    return fmaxf(v, 0.0f) + __logf(1.0f + __expf(-fabsf(v)));
}

__global__ __launch_bounds__(256) void spline_kernel(
    const float*    __restrict__ x,
    const uint16_t* __restrict__ outbuf,
    float* __restrict__ y,
    float* __restrict__ ldsum)
{
    const int b0  = blockIdx.x << 1;
    const int tid = threadIdx.x;
    const int r   = tid >> 7;          // row within block
    const int i   = tid & 127;         // spline element

    __shared__ uint4 sbuf[736];        // 2 * NOUT bf16 = 11776 B
    {
        const uint4* g = (const uint4*)(outbuf + (size_t)b0 * NOUT);
#pragma unroll
        for (int k = 0; k < 3; ++k) {
            int c = tid + k * 256;
            if (c < 736) sbuf[c] = g[c];
        }
    }
    __syncthreads();

    const uint16_t* srow = (const uint16_t*)sbuf + r * NOUT + i * OUT_MULT;
    float p[OUT_MULT];
#pragma unroll
    for (int k = 0; k < OUT_MULT; ++k) p[k] = bf2f(srow[k]);

    const float TAILF = 3.0f;
    const float MIN_W = 0.001f, MIN_H = 0.001f, MIN_D = 0.001f;
    const float INV_SCALE = 1.0f / 724.0773439350246f;   // 1/sqrt(H*H/2)

    const float xv = x[(size_t)(b0 + r) * N_IN + i];
    const float xc = fminf(fmaxf(xv, -TAILF), TAILF);

    float uw[NB], uh[NB];
#pragma unroll
    for (int k = 0; k < NB; ++k) { uw[k] = p[k] * INV_SCALE; uh[k] = p[NB + k] * INV_SCALE; }
    float mw = uw[0], mh = uh[0];
#pragma unroll
    for (int k = 1; k < NB; ++k) { mw = fmaxf(mw, uw[k]); mh = fmaxf(mh, uh[k]); }
    float ew[NB], eh[NB], sw = 0.0f, sh = 0.0f;
#pragma unroll
    for (int k = 0; k < NB; ++k) {
        ew[k] = __expf(uw[k] - mw); sw += ew[k];
        eh[k] = __expf(uh[k] - mh); sh += eh[k];
    }
    const float FACW = (1.0f - MIN_W * NB) * frcp(sw);
    const float FACH = (1.0f - MIN_H * NB) * frcp(sh);

    float cw[NB + 1], ch[NB + 1];
    cw[0] = -TAILF; ch[0] = -TAILF;
    float aw = 0.0f, ah = 0.0f;
#pragma unroll
    for (int k = 0; k < NB; ++k) {
        aw += MIN_W + FACW * ew[k];
        ah += MIN_H + FACH * eh[k];
        cw[k + 1] = (k == NB - 1) ? TAILF : 2.0f * TAILF * aw - TAILF;
        ch[k + 1] = (k == NB - 1) ? TAILF : 2.0f * TAILF * ah - TAILF;
    }

    float dd[NB + 1];
    dd[0]  = 1.0f;   // MIN_D + softplus(DPAD) == 0.001 + 0.999 exactly by construction
    dd[NB] = 1.0f;
#pragma unroll
    for (int k = 1; k < NB; ++k) dd[k] = MIN_D + softplusf(p[2 * NB + (k - 1)]);

    // bin select: largest k<=7 with xc >= cw[k]
    float in_cw = cw[0], cw_n = cw[1], in_ch = ch[0], ch_n = ch[1];
    float d0 = dd[0], d1 = dd[1];
#pragma unroll
    for (int k = 1; k < NB; ++k) {
        const bool ge = (xc >= cw[k]);
        in_cw = ge ? cw[k]     : in_cw;
        cw_n  = ge ? cw[k + 1] : cw_n;
        in_ch = ge ? ch[k]     : in_ch;
        ch_n  = ge ? ch[k + 1] : ch_n;
        d0    = ge ? dd[k]     : d0;
        d1    = ge ? dd[k + 1] : d1;
    }
    const float in_w  = cw_n - in_cw;
    const float in_h  = ch_n - in_ch;
    const float inv_w = frcp(in_w);
    const float delta = in_h * inv_w;
    const float theta = (xc - in_cw) * inv_w;
    const float omt   = 1.0f - theta;
    const float t1m   = theta * omt;
    const float denom = delta + (d0 + d1 - 2.0f * delta) * t1m;
    const float num   = in_h * (delta * theta * theta + d0 * t1m);
    float yv = in_ch + num * frcp(denom);
    float ld = 2.0f * __logf(delta)
             + __logf(d1 * theta * theta + 2.0f * delta * t1m + d0 * omt * omt)
             - 2.0f * __logf(denom);
    const bool inside = fabsf(xv) <= TAILF;
    yv = inside ? yv : xv;
    ld = inside ? ld : 0.0f;
    y[(size_t)(b0 + r) * N_IN + i] = yv;

    float v = ld;
#pragma unroll
    for (int o = 32; o > 0; o >>= 1) v += __shfl_down(v, o, 64);
    __shared__ float sred[4];
    const int w = tid >> 6;
    if ((tid & 63) == 0) sred[w] = v;
    __syncthreads();
    if (tid == 0)   ldsum[b0]     = sred[0] + sred[1];
    if (tid == 128) ldsum[b0 + 1] = sred[2] + sred[3];
}

// ---------------- host orchestration ----------------------------------------

extern "C" void kernel_launch(void* const* d_in, const int* in_sizes, int n_in,
                              void* d_out, int out_size, void* d_ws, size_t ws_size,
                              hipStream_t stream)
{
    const float* x     = (const float*)d_in[0];
    const float* ctx   = (const float*)d_in[1];
    const float* ctx_w = (const float*)d_in[2];
    const float* w0    = (const float*)d_in[3];
    const float* b0    = (const float*)d_in[4];
    const float* w1    = (const float*)d_in[5];
    const float* b1    = (const float*)d_in[6];
    const float* w2    = (const float*)d_in[7];
    const float* b2    = (const float*)d_in[8];
    // d_in[9..11] = masks: unused (computed analytically from indices)

    char* ws = (char*)d_ws;
    const size_t XCAT_B = (size_t)BATCH * KCAT * 2;   //   8 MB
    const size_t H2_B   = (size_t)BATCH * HDIM * 2;   //  32 MB
    const size_t WCAT_B = (size_t)HDIM * KCAT * 2;
    const size_t W1_B   = (size_t)HDIM * HDIM * 2;
    const size_t W2_B   = (size_t)NOUT * HDIM * 2;
    const size_t OUTH_B = (size_t)BATCH * NOUT * 2;   //  96 MB

    // out region [0,OUTH_B) aliases xcat+h1 (both dead before GEMM3 writes out)
    uint16_t* xcat = (uint16_t*)(ws);
    uint16_t* h1   = (uint16_t*)(ws + XCAT_B);
    uint16_t* outb = (uint16_t*)(ws);
    uint16_t* h2   = (uint16_t*)(ws + OUTH_B);
    uint16_t* wcat = (uint16_t*)(ws + OUTH_B + H2_B);
    uint16_t* w1m  = (uint16_t*)(ws + OUTH_B + H2_B + WCAT_B);
    uint16_t* w2m  = (uint16_t*)(ws + OUTH_B + H2_B + WCAT_B + W1_B);
    float*    b0p  = (float*)   (ws + OUTH_B + H2_B + WCAT_B + W1_B + W2_B);
    float*    b1p  = b0p + HDIM;

    float* yout  = (float*)d_out;
    float* ldout = yout + (size_t)BATCH * N_IN;

    pack_xcat<<<(BATCH * KCAT) / 256, 256, 0, stream>>>(x, ctx, xcat);
    pack_wcat<<<(HDIM * KCAT) / 256, 256, 0, stream>>>(ctx_w, w0, wcat);
    pack_w1  <<<(HDIM * HDIM) / 256, 256, 0, stream>>>(w1, w1m);
    pack_w2  <<<(NOUT * HDIM) / 256, 256, 0, stream>>>(w2, w2m);
    pack_bias<<<HDIM / 256, 256, 0, stream>>>(b0, b1, b0p, b1p);

    const dim3 blk(256);
    // 1D swizzled grid = MT * NT; K prefix per N-tile via MODE
    gemm_bt<0, 0><<<dim3(128 * (HDIM / 128)), blk, 0, stream>>>(
        xcat, wcat, b0p, h1, HDIM, KCAT, HDIM / 128);
    gemm_bt<0, 1><<<dim3(128 * (HDIM / 128)), blk, 0, stream>>>(
        h1, w1m, b1p, h2, HDIM, HDIM, HDIM / 128);
    gemm_bt<2, 2><<<dim3(128 * (NOUT / 128)), blk, 0, stream>>>(
        h2, w2m, b2, outb, NOUT, HDIM, NOUT / 128);

    spline_kernel<<<BATCH / 2, 256, 0, stream>>>(x, outb, yout, ldout);
}

// Round 4
// 253.101 us; speedup vs baseline: 1.5299x; 1.0526x over previous
//
#include <hip/hip_runtime.h>
#include <cstdint>
#include <cstddef>

#define BATCH   16384
#define N_IN    128
#define CTX     128
#define HDIM    1024
#define NB      8
#define OUT_MULT 23                 // 3*NB-1 (logical)
#define OUT_PAD 24                  // padded per-group width (col 23 = zeros)
#define NOUTP   (N_IN * OUT_PAD)    // 3072
#define KCAT    (CTX + N_IN)        // 256

typedef __bf16 bf16x8 __attribute__((ext_vector_type(8)));
typedef float  f32x4  __attribute__((ext_vector_type(4)));

__device__ __forceinline__ uint16_t f2bf(float f) {
    union { float f; uint32_t u; } v; v.f = f;
    uint32_t u = v.u;
    u += 0x7FFFu + ((u >> 16) & 1u);   // RNE
    return (uint16_t)(u >> 16);
}

// ---- degree-sorted permutation of the hidden dim ---------------------------
// deg(h) = h % 127; stable sort by deg. count(d) = 9 for d<8, 8 for d>=8.
// kpref(d) = #{h : deg(h) < d}; position p -> (d, occurrence j) -> h = d+127*j
__device__ __forceinline__ int kpref_dev(int d) {
    return (d <= 8) ? 9 * d : 72 + 8 * (d - 8);
}
__device__ __forceinline__ int dpos_dev(int p) {
    return (p < 72) ? (p / 9) : (8 + ((p - 72) >> 3));
}
__device__ __forceinline__ int h_of(int p) {
    if (p < 72) { int d = p / 9, j = p - 9 * d; return d + 127 * j; }
    int q = p - 72; int d = 8 + (q >> 3); int j = q & 7; return d + 127 * j;
}

// async global->LDS, 16B per lane; LDS dest = wave-uniform base + lane*16
__device__ __forceinline__ void async_ld16(const void* g, const void* l) {
    __builtin_amdgcn_global_load_lds(
        (__attribute__((address_space(1))) void*)(uintptr_t)g,
        (__attribute__((address_space(3))) void*)(uint32_t)(uintptr_t)l,
        16, 0, 0);
}

// ---------------- one fused pack kernel (masks analytic, degree-sorted) -----
// block ranges: [0,16384) xcat | [16384,17408) wcat | [17408,21504) w1
//               [21504,33792) w2p | [33792,33808) biases

__global__ void pack_all(
    const float* __restrict__ x,    const float* __restrict__ ctx,
    const float* __restrict__ ctx_w,const float* __restrict__ w0,
    const float* __restrict__ b0,   const float* __restrict__ w1,
    const float* __restrict__ b1,   const float* __restrict__ w2,
    const float* __restrict__ b2,
    uint16_t* __restrict__ xcat, uint16_t* __restrict__ wcat,
    uint16_t* __restrict__ w1m,  uint16_t* __restrict__ w2p,
    float* __restrict__ b0p, float* __restrict__ b1p, float* __restrict__ b2p)
{
    const int blk = blockIdx.x;
    const int tid = threadIdx.x;
    if (blk < 16384) {                       // xcat: BATCH x KCAT
        int idx = blk * 256 + tid;
        int b = idx >> 8, c = idx & 255;
        float v = (c < CTX) ? ctx[(b << 7) + c] : x[(b << 7) + (c - CTX)];
        xcat[idx] = f2bf(v);
    } else if (blk < 17408) {                // wcat: HDIM x KCAT, rows sorted
        int idx = (blk - 16384) * 256 + tid;
        int p = idx >> 8, c = idx & 255;
        int h = h_of(p);
        float v;
        if (c < CTX) v = ctx_w[(h << 7) + c];
        else {
            int col = c - CTX;               // mask0: dpos(p) >= col
            v = (dpos_dev(p) >= col) ? w0[(h << 7) + col] : 0.0f;
        }
        wcat[idx] = f2bf(v);
    } else if (blk < 21504) {                // w1: HDIM x HDIM, both sorted
        int idx = (blk - 17408) * 256 + tid;
        int po = idx >> 10, pi = idx & 1023;
        float v = (dpos_dev(po) >= dpos_dev(pi))
                ? w1[h_of(po) * HDIM + h_of(pi)] : 0.0f;
        w1m[idx] = f2bf(v);
    } else if (blk < 33792) {                // w2p: NOUTP x HDIM, K sorted, padded
        int idx = (blk - 21504) * 256 + tid;
        int oo = idx >> 10, pi = idx & 1023;
        int g = oo / OUT_PAD, t = oo - g * OUT_PAD;
        float v = (t < OUT_MULT && g > dpos_dev(pi))
                ? w2[(g * OUT_MULT + t) * HDIM + h_of(pi)] : 0.0f;
        w2p[idx] = f2bf(v);
    } else {                                 // biases
        int idx = (blk - 33792) * 256 + tid; // 0..4095
        if (idx < HDIM) {
            int h = h_of(idx);
            b0p[idx] = b0[h];
            b1p[idx] = b1[h];
        } else {
            int oo = idx - HDIM;             // 0..3071
            int g = oo / OUT_PAD, t = oo - g * OUT_PAD;
            b2p[oo] = (t < OUT_MULT) ? b2[g * OUT_MULT + t] : 0.0f;
        }
    }
}

// ---------------- bf16 GEMM, C = A(MxK) @ B(NxK)^T + bias (relu, bf16 out) --
// MODE selects the per-N-tile K prefix (degree-sorted masks => zero tail):
//   0: GEMM1  K_eff = 128 + dmax + 1
//   1: GEMM2  K_eff = kpref(dmax+1)

template<int MODE>
__global__ __launch_bounds__(256, 2) void gemm_bt(
    const uint16_t* __restrict__ A,
    const uint16_t* __restrict__ B,
    const float*    __restrict__ bias,
    uint16_t*       __restrict__ C,
    int N, int K, int NT)
{
    __shared__ __align__(16) uint16_t sA[128 * 32];
    __shared__ __align__(16) uint16_t sB[128 * 32];

    const int GM    = 64;
    const int per   = GM * NT;
    const int id    = blockIdx.x;
    const int grp   = id / per;
    const int rem   = id - grp * per;
    const int mt    = grp * GM + (rem & (GM - 1));
    const int nt    = rem >> 6;
    const int bm    = mt << 7;
    const int bn    = nt << 7;

    int K_eff;
    if (MODE == 0)      { int dmax = dpos_dev(bn + 127); K_eff = 128 + dmax + 1; }
    else                { int dmax = dpos_dev(bn + 127); K_eff = kpref_dev(dmax + 1); }
    K_eff = min(K, (K_eff + 31) & ~31);

    const int tid   = threadIdx.x;
    const int wid   = tid >> 6;
    const int lane  = tid & 63;
    const int wm    = (wid & 1) << 6;
    const int wn    = (wid >> 1) << 6;
    const int lrow  = lane & 15;
    const int lquad = lane >> 4;

    const f32x4 vzero = {0.0f, 0.0f, 0.0f, 0.0f};
    f32x4 acc[4][4];
#pragma unroll
    for (int i = 0; i < 4; ++i)
#pragma unroll
        for (int j = 0; j < 4; ++j) acc[i][j] = vzero;

    const int c0 = (wid << 6) + lane;
    const int c1 = c0 + 256;
    const char* gA = (const char*)(A + (size_t)bm * K);
    const char* gB = (const char*)(B + (size_t)bn * K);
    const size_t ga0 = (size_t)(c0 >> 2) * K * 2 + (size_t)(c0 & 3) * 16;
    const size_t ga1 = (size_t)(c1 >> 2) * K * 2 + (size_t)(c1 & 3) * 16;
    const char* lA0 = (const char*)sA + (size_t)(wid << 6) * 16;
    const char* lA1 = lA0 + 256 * 16;
    const char* lB0 = (const char*)sB + (size_t)(wid << 6) * 16;
    const char* lB1 = lB0 + 256 * 16;

    const uint16_t* rA = sA + (wm + lrow) * 32 + lquad * 8;
    const uint16_t* rB = sB + (wn + lrow) * 32 + lquad * 8;

    for (int k0 = 0; k0 < K_eff; k0 += 32) {
        __syncthreads();
        const size_t kb = (size_t)k0 * 2;
        async_ld16(gA + ga0 + kb, lA0);
        async_ld16(gA + ga1 + kb, lA1);
        async_ld16(gB + ga0 + kb, lB0);
        async_ld16(gB + ga1 + kb, lB1);
        __syncthreads();

        bf16x8 af[4], bfr[4];
#pragma unroll
        for (int i = 0; i < 4; ++i) af[i]  = *(const bf16x8*)(rA + i * 16 * 32);
#pragma unroll
        for (int j = 0; j < 4; ++j) bfr[j] = *(const bf16x8*)(rB + j * 16 * 32);
#pragma unroll
        for (int i = 0; i < 4; ++i)
#pragma unroll
            for (int j = 0; j < 4; ++j)
                acc[i][j] = __builtin_amdgcn_mfma_f32_16x16x32_bf16(
                                af[i], bfr[j], acc[i][j], 0, 0, 0);
    }

#pragma unroll
    for (int j = 0; j < 4; ++j) {
        const int col = bn + wn + j * 16 + lrow;
        const float bv = bias[col];
#pragma unroll
        for (int i = 0; i < 4; ++i) {
            const int row0 = bm + wm + i * 16 + (lquad << 2);
#pragma unroll
            for (int r = 0; r < 4; ++r) {
                float v = fmaxf(acc[i][j][r] + bv, 0.0f);
                C[(size_t)(row0 + r) * N + col] = f2bf(v);
            }
        }
    }
}

// ---------------- spline evaluation (f32 params, HW transcendentals) --------

__device__ __forceinline__ float frcp(float v) { return __builtin_amdgcn_rcpf(v); }
__device__ __forceinline__ float softplusf(float v) {
    return fmaxf(v, 0.0f) + __logf(1.0f + __expf(-fabsf(v)));
}

__device__ __forceinline__ void spline_eval(const float* __restrict__ pp,
                                            float xv, float& yout, float& ldout)
{
    float p[OUT_MULT];
#pragma unroll
    for (int k = 0; k < OUT_MULT; ++k) p[k] = pp[k];

    const float TAILF = 3.0f;
    const float MIN_W = 0.001f, MIN_H = 0.001f, MIN_D = 0.001f;
    const float INV_SCALE = 1.0f / 724.0773439350246f;   // 1/sqrt(H*H/2)

    const float xc = fminf(fmaxf(xv, -TAILF), TAILF);

    float uw[NB], uh[NB];
#pragma unroll
    for (int k = 0; k < NB; ++k) { uw[k] = p[k] * INV_SCALE; uh[k] = p[NB + k] * INV_SCALE; }
    float mw = uw[0], mh = uh[0];
#pragma unroll
    for (int k = 1; k < NB; ++k) { mw = fmaxf(mw, uw[k]); mh = fmaxf(mh, uh[k]); }
    float ew[NB], eh[NB], sw = 0.0f, sh = 0.0f;
#pragma unroll
    for (int k = 0; k < NB; ++k) {
        ew[k] = __expf(uw[k] - mw); sw += ew[k];
        eh[k] = __expf(uh[k] - mh); sh += eh[k];
    }
    const float FACW = (1.0f - MIN_W * NB) * frcp(sw);
    const float FACH = (1.0f - MIN_H * NB) * frcp(sh);

    float cw[NB + 1], ch[NB + 1];
    cw[0] = -TAILF; ch[0] = -TAILF;
    float aw = 0.0f, ah = 0.0f;
#pragma unroll
    for (int k = 0; k < NB; ++k) {
        aw += MIN_W + FACW * ew[k];
        ah += MIN_H + FACH * eh[k];
        cw[k + 1] = (k == NB - 1) ? TAILF : 2.0f * TAILF * aw - TAILF;
        ch[k + 1] = (k == NB - 1) ? TAILF : 2.0f * TAILF * ah - TAILF;
    }

    float dd[NB + 1];
    dd[0]  = 1.0f;   // MIN_D + softplus(DPAD) == 1 exactly by construction
    dd[NB] = 1.0f;
#pragma unroll
    for (int k = 1; k < NB; ++k) dd[k] = MIN_D + softplusf(p[2 * NB + (k - 1)]);

    float in_cw = cw[0], cw_n = cw[1], in_ch = ch[0], ch_n = ch[1];
    float d0 = dd[0], d1 = dd[1];
#pragma unroll
    for (int k = 1; k < NB; ++k) {
        const bool ge = (xc >= cw[k]);
        in_cw = ge ? cw[k]     : in_cw;
        cw_n  = ge ? cw[k + 1] : cw_n;
        in_ch = ge ? ch[k]     : in_ch;
        ch_n  = ge ? ch[k + 1] : ch_n;
        d0    = ge ? dd[k]     : d0;
        d1    = ge ? dd[k + 1] : d1;
    }
    const float in_w  = cw_n - in_cw;
    const float in_h  = ch_n - in_ch;
    const float inv_w = frcp(in_w);
    const float delta = in_h * inv_w;
    const float theta = (xc - in_cw) * inv_w;
    const float omt   = 1.0f - theta;
    const float t1m   = theta * omt;
    const float denom = delta + (d0 + d1 - 2.0f * delta) * t1m;
    const float num   = in_h * (delta * theta * theta + d0 * t1m);
    float yv = in_ch + num * frcp(denom);
    float ld = 2.0f * __logf(delta)
             + __logf(d1 * theta * theta + 2.0f * delta * t1m + d0 * omt * omt)
             - 2.0f * __logf(denom);
    const bool inside = fabsf(xv) <= TAILF;
    yout  = inside ? yv : xv;
    ldout = inside ? ld : 0.0f;
}

// ---------------- fused GEMM3 + spline --------------------------------------
// Block tile: 128 M x 96 N (= 4 complete padded groups). Waves 2x2: 64 x 48.
// K prefix per tile: kpref(4*nt+3) -- exactly 32*(nt+1), no rounding waste.
// Epilogue: acc+bias -> LDS f32 (stride 97), per-thread spline on 2 elements,
// y via float4 staging, logdet via per-row atomicAdd (ldsum pre-zeroed).

__global__ __launch_bounds__(256, 2) void gemm3_spline(
    const uint16_t* __restrict__ A,      // h2: BATCH x HDIM (sorted K)
    const uint16_t* __restrict__ B,      // w2p: NOUTP x HDIM
    const float*    __restrict__ bias,   // b2p: NOUTP
    const float*    __restrict__ x,      // BATCH x N_IN
    float* __restrict__ y,
    float* __restrict__ ldsum)
{
    __shared__ __align__(16) char smem[52224];
    uint16_t* sA = (uint16_t*)smem;                 // 128*32*2 = 8192
    uint16_t* sB = (uint16_t*)(smem + 8192);        //  96*32*2 = 6144
    float* ep    = (float*)smem;                    // 128*97*4 = 49664 (aliases staging)
    float* ytile = (float*)(smem + 49664);          // 128*4*4  = 2048
    float* ldp   = (float*)(smem + 51712);          // 128*4    = 512

    const int NT  = 32;
    const int per = 64 * NT;                        // 2048
    const int id  = blockIdx.x;
    const int grp = id / per;
    const int rem = id - grp * per;
    const int mt  = grp * 64 + (rem & 63);
    const int nt  = rem >> 6;
    const int bm  = mt << 7;
    const int bn  = nt * 96;

    const int K = HDIM;
    int K_eff = kpref_dev(4 * nt + 3);
    K_eff = min(K, (K_eff + 31) & ~31);

    const int tid   = threadIdx.x;
    const int wid   = tid >> 6;
    const int lane  = tid & 63;
    const int wm    = (wid & 1) << 6;
    const int wn    = (wid >> 1) * 48;
    const int lrow  = lane & 15;
    const int lquad = lane >> 4;

    const f32x4 vzero = {0.0f, 0.0f, 0.0f, 0.0f};
    f32x4 acc[4][3];
#pragma unroll
    for (int i = 0; i < 4; ++i)
#pragma unroll
        for (int j = 0; j < 3; ++j) acc[i][j] = vzero;

    // A staging: 512 chunks (2/thread). B staging: 384 chunks (waves 0-3 one,
    // waves 0-1 a second). chunk c -> row c>>2, k-sub (c&3)*8.
    const int cA0 = (wid << 6) + lane;
    const int cA1 = cA0 + 256;
    const int cB1 = 256 + (wid << 6) + lane;        // only wid<2
    const char* gA = (const char*)(A + (size_t)bm * K);
    const char* gB = (const char*)(B + (size_t)bn * K);
    const size_t gaA0 = (size_t)(cA0 >> 2) * K * 2 + (size_t)(cA0 & 3) * 16;
    const size_t gaA1 = (size_t)(cA1 >> 2) * K * 2 + (size_t)(cA1 & 3) * 16;
    const size_t gaB0 = gaA0;                        // same chunk index
    const size_t gaB1 = (size_t)(cB1 >> 2) * K * 2 + (size_t)(cB1 & 3) * 16;
    const char* lA0 = (const char*)sA + (size_t)(wid << 6) * 16;
    const char* lA1 = lA0 + 256 * 16;
    const char* lB0 = (const char*)sB + (size_t)(wid << 6) * 16;
    const char* lB1 = (const char*)sB + 4096 + (size_t)(wid << 6) * 16;

    const uint16_t* rA = sA + (wm + lrow) * 32 + lquad * 8;
    const uint16_t* rB = sB + (wn + lrow) * 32 + lquad * 8;

    for (int k0 = 0; k0 < K_eff; k0 += 32) {
        __syncthreads();
        const size_t kb = (size_t)k0 * 2;
        async_ld16(gA + gaA0 + kb, lA0);
        async_ld16(gA + gaA1 + kb, lA1);
        async_ld16(gB + gaB0 + kb, lB0);
        if (wid < 2) async_ld16(gB + gaB1 + kb, lB1);
        __syncthreads();

        bf16x8 af[4], bfr[3];
#pragma unroll
        for (int i = 0; i < 4; ++i) af[i]  = *(const bf16x8*)(rA + i * 16 * 32);
#pragma unroll
        for (int j = 0; j < 3; ++j) bfr[j] = *(const bf16x8*)(rB + j * 16 * 32);
#pragma unroll
        for (int i = 0; i < 4; ++i)
#pragma unroll
            for (int j = 0; j < 3; ++j)
                acc[i][j] = __builtin_amdgcn_mfma_f32_16x16x32_bf16(
                                af[i], bfr[j], acc[i][j], 0, 0, 0);
    }

    __syncthreads();        // all waves done with sA/sB before ep overwrite

    // acc + bias -> ep[row*97 + col]
#pragma unroll
    for (int j = 0; j < 3; ++j) {
        const int col = wn + j * 16 + lrow;
        const float bv = bias[bn + col];
#pragma unroll
        for (int i = 0; i < 4; ++i) {
            const int row0 = wm + i * 16 + (lquad << 2);
#pragma unroll
            for (int r = 0; r < 4; ++r)
                ep[(row0 + r) * 97 + col] = acc[i][j][r] + bv;
        }
    }
    __syncthreads();

    // spline: thread handles (row, g0) and (row, g0+2)
    const int row = tid & 127;
    const int g0  = tid >> 7;
    float ldacc = 0.0f;
#pragma unroll
    for (int e = 0; e < 2; ++e) {
        const int g = g0 + 2 * e;
        const float xv = x[(size_t)(bm + row) * N_IN + (4 * nt + g)];
        float yv, ld;
        spline_eval(ep + row * 97 + g * OUT_PAD, xv, yv, ld);
        ytile[row * 4 + g] = yv;
        ldacc += ld;
    }
    if (g0 == 1) ldp[row] = ldacc;
    __syncthreads();
    if (g0 == 0) {
        atomicAdd(&ldsum[bm + row], ldacc + ldp[row]);
        const f32x4 v = *(const f32x4*)(ytile + row * 4);
        *(f32x4*)(&y[(size_t)(bm + row) * N_IN + 4 * nt]) = v;
    }
}

// ---------------- host orchestration ----------------------------------------

extern "C" void kernel_launch(void* const* d_in, const int* in_sizes, int n_in,
                              void* d_out, int out_size, void* d_ws, size_t ws_size,
                              hipStream_t stream)
{
    const float* x     = (const float*)d_in[0];
    const float* ctx   = (const float*)d_in[1];
    const float* ctx_w = (const float*)d_in[2];
    const float* w0    = (const float*)d_in[3];
    const float* b0    = (const float*)d_in[4];
    const float* w1    = (const float*)d_in[5];
    const float* b1    = (const float*)d_in[6];
    const float* w2    = (const float*)d_in[7];
    const float* b2    = (const float*)d_in[8];
    // d_in[9..11] = masks: unused (computed analytically from indices)

    char* ws = (char*)d_ws;
    const size_t XCAT_B = (size_t)BATCH * KCAT * 2;   //   8 MB
    const size_t H_B    = (size_t)BATCH * HDIM * 2;   //  32 MB each
    const size_t WCAT_B = (size_t)HDIM * KCAT * 2;
    const size_t W1_B   = (size_t)HDIM * HDIM * 2;
    const size_t W2P_B  = (size_t)NOUTP * HDIM * 2;

    uint16_t* xcat = (uint16_t*)(ws);
    uint16_t* h1   = (uint16_t*)(ws + XCAT_B);
    uint16_t* h2   = (uint16_t*)(ws + XCAT_B + H_B);
    uint16_t* wcat = (uint16_t*)(ws + XCAT_B + 2 * H_B);
    uint16_t* w1m  = (uint16_t*)(ws + XCAT_B + 2 * H_B + WCAT_B);
    uint16_t* w2p  = (uint16_t*)(ws + XCAT_B + 2 * H_B + WCAT_B + W1_B);
    float*    b0p  = (float*)   (ws + XCAT_B + 2 * H_B + WCAT_B + W1_B + W2P_B);
    float*    b1p  = b0p + HDIM;
    float*    b2p  = b1p + HDIM;

    float* yout  = (float*)d_out;
    float* ldout = yout + (size_t)BATCH * N_IN;

    hipMemsetAsync(ldout, 0, (size_t)BATCH * sizeof(float), stream);

    pack_all<<<33808, 256, 0, stream>>>(x, ctx, ctx_w, w0, b0, w1, b1, w2, b2,
                                        xcat, wcat, w1m, w2p, b0p, b1p, b2p);

    const dim3 blk(256);
    gemm_bt<0><<<dim3(128 * (HDIM / 128)), blk, 0, stream>>>(
        xcat, wcat, b0p, h1, HDIM, KCAT, HDIM / 128);
    gemm_bt<1><<<dim3(128 * (HDIM / 128)), blk, 0, stream>>>(
        h1, w1m, b1p, h2, HDIM, HDIM, HDIM / 128);
    gemm3_spline<<<dim3(128 * 32), blk, 0, stream>>>(
        h2, w2p, b2p, x, yout, ldout);
}

// Round 5
// 247.944 us; speedup vs baseline: 1.5617x; 1.0208x over previous
//
#include <hip/hip_runtime.h>
#include <cstdint>
#include <cstddef>

#define BATCH   16384
#define N_IN    128
#define CTX     128
#define HDIM    1024
#define NB      8
#define OUT_MULT 23                 // 3*NB-1 (logical)
#define OUT_PAD 24                  // padded per-group width (col 23 = zeros)
#define NOUTP   (N_IN * OUT_PAD)    // 3072
#define KCAT    (CTX + N_IN)        // 256

typedef __bf16 bf16x8 __attribute__((ext_vector_type(8)));
typedef float  f32x4  __attribute__((ext_vector_type(4)));

__device__ __forceinline__ uint16_t f2bf(float f) {
    union { float f; uint32_t u; } v; v.f = f;
    uint32_t u = v.u;
    u += 0x7FFFu + ((u >> 16) & 1u);   // RNE
    return (uint16_t)(u >> 16);
}

// ---- degree-sorted permutation of the hidden dim ---------------------------
// deg(h) = h % 127; stable sort by deg. count(d) = 9 for d<8, 8 for d>=8.
// kpref(d) = #{h : deg(h) < d}; position p -> (d, occurrence j) -> h = d+127*j
__device__ __forceinline__ int kpref_dev(int d) {
    return (d <= 8) ? 9 * d : 72 + 8 * (d - 8);
}
__device__ __forceinline__ int dpos_dev(int p) {
    return (p < 72) ? (p / 9) : (8 + ((p - 72) >> 3));
}
__device__ __forceinline__ int h_of(int p) {
    if (p < 72) { int d = p / 9, j = p - 9 * d; return d + 127 * j; }
    int q = p - 72; int d = 8 + (q >> 3); int j = q & 7; return d + 127 * j;
}

// async global->LDS, 16B per lane; LDS dest = wave-uniform base + lane*16
__device__ __forceinline__ void async_ld16(const void* g, const void* l) {
    __builtin_amdgcn_global_load_lds(
        (__attribute__((address_space(1))) void*)(uintptr_t)g,
        (__attribute__((address_space(3))) void*)(uint32_t)(uintptr_t)l,
        16, 0, 0);
}

// ---------------- one fused pack kernel (masks analytic, degree-sorted) -----
// block ranges: [0,16384) xcat | [16384,17408) wcat | [17408,21504) w1
//               [21504,33792) w2p | [33792,33808) biases | [33808,33872) ld=0

__global__ void pack_all(
    const float* __restrict__ x,    const float* __restrict__ ctx,
    const float* __restrict__ ctx_w,const float* __restrict__ w0,
    const float* __restrict__ b0,   const float* __restrict__ w1,
    const float* __restrict__ b1,   const float* __restrict__ w2,
    const float* __restrict__ b2,
    uint16_t* __restrict__ xcat, uint16_t* __restrict__ wcat,
    uint16_t* __restrict__ w1m,  uint16_t* __restrict__ w2p,
    float* __restrict__ b0p, float* __restrict__ b1p, float* __restrict__ b2p,
    float* __restrict__ ldz)
{
    const int blk = blockIdx.x;
    const int tid = threadIdx.x;
    if (blk < 16384) {                       // xcat: BATCH x KCAT
        int idx = blk * 256 + tid;
        int b = idx >> 8, c = idx & 255;
        float v = (c < CTX) ? ctx[(b << 7) + c] : x[(b << 7) + (c - CTX)];
        xcat[idx] = f2bf(v);
    } else if (blk < 17408) {                // wcat: HDIM x KCAT, rows sorted
        int idx = (blk - 16384) * 256 + tid;
        int p = idx >> 8, c = idx & 255;
        int h = h_of(p);
        float v;
        if (c < CTX) v = ctx_w[(h << 7) + c];
        else {
            int col = c - CTX;               // mask0: dpos(p) >= col
            v = (dpos_dev(p) >= col) ? w0[(h << 7) + col] : 0.0f;
        }
        wcat[idx] = f2bf(v);
    } else if (blk < 21504) {                // w1: HDIM x HDIM, both sorted
        int idx = (blk - 17408) * 256 + tid;
        int po = idx >> 10, pi = idx & 1023;
        float v = (dpos_dev(po) >= dpos_dev(pi))
                ? w1[h_of(po) * HDIM + h_of(pi)] : 0.0f;
        w1m[idx] = f2bf(v);
    } else if (blk < 33792) {                // w2p: NOUTP x HDIM, K sorted, padded
        int idx = (blk - 21504) * 256 + tid;
        int oo = idx >> 10, pi = idx & 1023;
        int g = oo / OUT_PAD, t = oo - g * OUT_PAD;
        float v = (t < OUT_MULT && g > dpos_dev(pi))
                ? w2[(g * OUT_MULT + t) * HDIM + h_of(pi)] : 0.0f;
        w2p[idx] = f2bf(v);
    } else if (blk < 33808) {                // biases
        int idx = (blk - 33792) * 256 + tid; // 0..4095
        if (idx < HDIM) {
            int h = h_of(idx);
            b0p[idx] = b0[h];
            b1p[idx] = b1[h];
        } else {
            int oo = idx - HDIM;             // 0..3071
            int g = oo / OUT_PAD, t = oo - g * OUT_PAD;
            b2p[oo] = (t < OUT_MULT) ? b2[g * OUT_MULT + t] : 0.0f;
        }
    } else {                                 // zero ldsum (BATCH floats)
        int idx = (blk - 33808) * 256 + tid;
        ldz[idx] = 0.0f;
    }
}

// ---------------- bf16 GEMM, C = A(MxK) @ B(NxK)^T + bias (relu, bf16 out) --
// MODE selects the per-N-tile K prefix (degree-sorted masks => zero tail):
//   0: GEMM1  K_eff = 128 + dmax + 1
//   1: GEMM2  K_eff = kpref(dmax+1)

template<int MODE>
__global__ __launch_bounds__(256, 2) void gemm_bt(
    const uint16_t* __restrict__ A,
    const uint16_t* __restrict__ B,
    const float*    __restrict__ bias,
    uint16_t*       __restrict__ C,
    int N, int K, int NT)
{
    __shared__ __align__(16) uint16_t sA[128 * 32];
    __shared__ __align__(16) uint16_t sB[128 * 32];

    const int GM    = 64;
    const int per   = GM * NT;
    const int id    = blockIdx.x;
    const int grp   = id / per;
    const int rem   = id - grp * per;
    const int mt    = grp * GM + (rem & (GM - 1));
    const int nt    = rem >> 6;
    const int bm    = mt << 7;
    const int bn    = nt << 7;

    int K_eff;
    if (MODE == 0)      { int dmax = dpos_dev(bn + 127); K_eff = 128 + dmax + 1; }
    else                { int dmax = dpos_dev(bn + 127); K_eff = kpref_dev(dmax + 1); }
    K_eff = min(K, (K_eff + 31) & ~31);

    const int tid   = threadIdx.x;
    const int wid   = tid >> 6;
    const int lane  = tid & 63;
    const int wm    = (wid & 1) << 6;
    const int wn    = (wid >> 1) << 6;
    const int lrow  = lane & 15;
    const int lquad = lane >> 4;

    const f32x4 vzero = {0.0f, 0.0f, 0.0f, 0.0f};
    f32x4 acc[4][4];
#pragma unroll
    for (int i = 0; i < 4; ++i)
#pragma unroll
        for (int j = 0; j < 4; ++j) acc[i][j] = vzero;

    const int c0 = (wid << 6) + lane;
    const int c1 = c0 + 256;
    const char* gA = (const char*)(A + (size_t)bm * K);
    const char* gB = (const char*)(B + (size_t)bn * K);
    const size_t ga0 = (size_t)(c0 >> 2) * K * 2 + (size_t)(c0 & 3) * 16;
    const size_t ga1 = (size_t)(c1 >> 2) * K * 2 + (size_t)(c1 & 3) * 16;
    const char* lA0 = (const char*)sA + (size_t)(wid << 6) * 16;
    const char* lA1 = lA0 + 256 * 16;
    const char* lB0 = (const char*)sB + (size_t)(wid << 6) * 16;
    const char* lB1 = lB0 + 256 * 16;

    const uint16_t* rA = sA + (wm + lrow) * 32 + lquad * 8;
    const uint16_t* rB = sB + (wn + lrow) * 32 + lquad * 8;

    for (int k0 = 0; k0 < K_eff; k0 += 32) {
        __syncthreads();
        const size_t kb = (size_t)k0 * 2;
        async_ld16(gA + ga0 + kb, lA0);
        async_ld16(gA + ga1 + kb, lA1);
        async_ld16(gB + ga0 + kb, lB0);
        async_ld16(gB + ga1 + kb, lB1);
        __syncthreads();

        bf16x8 af[4], bfr[4];
#pragma unroll
        for (int i = 0; i < 4; ++i) af[i]  = *(const bf16x8*)(rA + i * 16 * 32);
#pragma unroll
        for (int j = 0; j < 4; ++j) bfr[j] = *(const bf16x8*)(rB + j * 16 * 32);
#pragma unroll
        for (int i = 0; i < 4; ++i)
#pragma unroll
            for (int j = 0; j < 4; ++j)
                acc[i][j] = __builtin_amdgcn_mfma_f32_16x16x32_bf16(
                                af[i], bfr[j], acc[i][j], 0, 0, 0);
    }

#pragma unroll
    for (int j = 0; j < 4; ++j) {
        const int col = bn + wn + j * 16 + lrow;
        const float bv = bias[col];
#pragma unroll
        for (int i = 0; i < 4; ++i) {
            const int row0 = bm + wm + i * 16 + (lquad << 2);
#pragma unroll
            for (int r = 0; r < 4; ++r) {
                float v = fmaxf(acc[i][j][r] + bv, 0.0f);
                C[(size_t)(row0 + r) * N + col] = f2bf(v);
            }
        }
    }
}

// ---------------- spline evaluation (f32 params, HW transcendentals) --------

__device__ __forceinline__ float frcp(float v) { return __builtin_amdgcn_rcpf(v); }
__device__ __forceinline__ float softplusf(float v) {
    return fmaxf(v, 0.0f) + __logf(1.0f + __expf(-fabsf(v)));
}

__device__ __forceinline__ void spline_eval(const float* __restrict__ pp,
                                            float xv, float& yout, float& ldout)
{
    float p[OUT_MULT];
#pragma unroll
    for (int k = 0; k < OUT_MULT; ++k) p[k] = pp[k];

    const float TAILF = 3.0f;
    const float MIN_W = 0.001f, MIN_H = 0.001f, MIN_D = 0.001f;
    const float INV_SCALE = 1.0f / 724.0773439350246f;   // 1/sqrt(H*H/2)

    const float xc = fminf(fmaxf(xv, -TAILF), TAILF);

    float uw[NB], uh[NB];
#pragma unroll
    for (int k = 0; k < NB; ++k) { uw[k] = p[k] * INV_SCALE; uh[k] = p[NB + k] * INV_SCALE; }
    float mw = uw[0], mh = uh[0];
#pragma unroll
    for (int k = 1; k < NB; ++k) { mw = fmaxf(mw, uw[k]); mh = fmaxf(mh, uh[k]); }
    float ew[NB], eh[NB], sw = 0.0f, sh = 0.0f;
#pragma unroll
    for (int k = 0; k < NB; ++k) {
        ew[k] = __expf(uw[k] - mw); sw += ew[k];
        eh[k] = __expf(uh[k] - mh); sh += eh[k];
    }
    const float FACW = (1.0f - MIN_W * NB) * frcp(sw);
    const float FACH = (1.0f - MIN_H * NB) * frcp(sh);

    float cw[NB + 1], ch[NB + 1];
    cw[0] = -TAILF; ch[0] = -TAILF;
    float aw = 0.0f, ah = 0.0f;
#pragma unroll
    for (int k = 0; k < NB; ++k) {
        aw += MIN_W + FACW * ew[k];
        ah += MIN_H + FACH * eh[k];
        cw[k + 1] = (k == NB - 1) ? TAILF : 2.0f * TAILF * aw - TAILF;
        ch[k + 1] = (k == NB - 1) ? TAILF : 2.0f * TAILF * ah - TAILF;
    }

    float dd[NB + 1];
    dd[0]  = 1.0f;   // MIN_D + softplus(DPAD) == 1 exactly by construction
    dd[NB] = 1.0f;
#pragma unroll
    for (int k = 1; k < NB; ++k) dd[k] = MIN_D + softplusf(p[2 * NB + (k - 1)]);

    float in_cw = cw[0], cw_n = cw[1], in_ch = ch[0], ch_n = ch[1];
    float d0 = dd[0], d1 = dd[1];
#pragma unroll
    for (int k = 1; k < NB; ++k) {
        const bool ge = (xc >= cw[k]);
        in_cw = ge ? cw[k]     : in_cw;
        cw_n  = ge ? cw[k + 1] : cw_n;
        in_ch = ge ? ch[k]     : in_ch;
        ch_n  = ge ? ch[k + 1] : ch_n;
        d0    = ge ? dd[k]     : d0;
        d1    = ge ? dd[k + 1] : d1;
    }
    const float in_w  = cw_n - in_cw;
    const float in_h  = ch_n - in_ch;
    const float inv_w = frcp(in_w);
    const float delta = in_h * inv_w;
    const float theta = (xc - in_cw) * inv_w;
    const float omt   = 1.0f - theta;
    const float t1m   = theta * omt;
    const float denom = delta + (d0 + d1 - 2.0f * delta) * t1m;
    const float num   = in_h * (delta * theta * theta + d0 * t1m);
    float yv = in_ch + num * frcp(denom);
    float ld = 2.0f * __logf(delta)
             + __logf(d1 * theta * theta + 2.0f * delta * t1m + d0 * omt * omt)
             - 2.0f * __logf(denom);
    const bool inside = fabsf(xv) <= TAILF;
    yout  = inside ? yv : xv;
    ldout = inside ? ld : 0.0f;
}

// ---------------- fused GEMM3 + spline --------------------------------------
// Block tile: 128 M x 96 N (= 4 complete padded groups). Waves 2x2: 64 x 48.
// K prefix per tile: kpref(4*nt+3) = 32*(nt+1) exactly, no rounding waste.
// Two-phase epilogue (rows 0-63, then 64-127) through a 64x97 f32 LDS tile
// that aliases the dead staging buffers: LDS block = 24.8 KB (occupancy!).
// Spline thread map tid=4*row+g -> ep reads are 2 lanes/bank (free, m136).
// logdet: quad shuffle-reduce, one atomicAdd per row (ldsum pre-zeroed).

__global__ __launch_bounds__(256, 2) void gemm3_spline(
    const uint16_t* __restrict__ A,      // h2: BATCH x HDIM (sorted K)
    const uint16_t* __restrict__ B,      // w2p: NOUTP x HDIM
    const float*    __restrict__ bias,   // b2p: NOUTP
    const float*    __restrict__ x,      // BATCH x N_IN
    float* __restrict__ y,
    float* __restrict__ ldsum)
{
    __shared__ __align__(16) char smem[64 * 97 * 4];   // 24832 B
    uint16_t* sA = (uint16_t*)smem;                 // 128*32*2 = 8192
    uint16_t* sB = (uint16_t*)(smem + 8192);        //  96*32*2 = 6144
    float* ep    = (float*)smem;                    // 64*97*4 (aliases staging)

    const int NT  = 32;
    const int per = 64 * NT;                        // 2048
    const int id  = blockIdx.x;
    const int grp = id / per;
    const int rem = id - grp * per;
    const int mt  = grp * 64 + (rem & 63);
    const int nt  = rem >> 6;
    const int bm  = mt << 7;
    const int bn  = nt * 96;

    const int K = HDIM;
    int K_eff = kpref_dev(4 * nt + 3);
    K_eff = min(K, (K_eff + 31) & ~31);

    const int tid   = threadIdx.x;
    const int wid   = tid >> 6;
    const int lane  = tid & 63;
    const int wm    = (wid & 1) << 6;
    const int wn    = (wid >> 1) * 48;
    const int lrow  = lane & 15;
    const int lquad = lane >> 4;

    const f32x4 vzero = {0.0f, 0.0f, 0.0f, 0.0f};
    f32x4 acc[4][3];
#pragma unroll
    for (int i = 0; i < 4; ++i)
#pragma unroll
        for (int j = 0; j < 3; ++j) acc[i][j] = vzero;

    // A staging: 512 chunks (2/thread). B staging: 384 chunks (all waves one,
    // waves 0-1 a second). chunk c -> row c>>2, k-sub (c&3)*8.
    const int cA0 = (wid << 6) + lane;
    const int cA1 = cA0 + 256;
    const int cB1 = 256 + (wid << 6) + lane;        // only wid<2
    const char* gA = (const char*)(A + (size_t)bm * K);
    const char* gB = (const char*)(B + (size_t)bn * K);
    const size_t gaA0 = (size_t)(cA0 >> 2) * K * 2 + (size_t)(cA0 & 3) * 16;
    const size_t gaA1 = (size_t)(cA1 >> 2) * K * 2 + (size_t)(cA1 & 3) * 16;
    const size_t gaB0 = gaA0;
    const size_t gaB1 = (size_t)(cB1 >> 2) * K * 2 + (size_t)(cB1 & 3) * 16;
    const char* lA0 = (const char*)sA + (size_t)(wid << 6) * 16;
    const char* lA1 = lA0 + 256 * 16;
    const char* lB0 = (const char*)sB + (size_t)(wid << 6) * 16;
    const char* lB1 = (const char*)sB + 4096 + (size_t)(wid << 6) * 16;

    const uint16_t* rA = sA + (wm + lrow) * 32 + lquad * 8;
    const uint16_t* rB = sB + (wn + lrow) * 32 + lquad * 8;

    for (int k0 = 0; k0 < K_eff; k0 += 32) {
        __syncthreads();
        const size_t kb = (size_t)k0 * 2;
        async_ld16(gA + gaA0 + kb, lA0);
        async_ld16(gA + gaA1 + kb, lA1);
        async_ld16(gB + gaB0 + kb, lB0);
        if (wid < 2) async_ld16(gB + gaB1 + kb, lB1);
        __syncthreads();

        bf16x8 af[4], bfr[3];
#pragma unroll
        for (int i = 0; i < 4; ++i) af[i]  = *(const bf16x8*)(rA + i * 16 * 32);
#pragma unroll
        for (int j = 0; j < 3; ++j) bfr[j] = *(const bf16x8*)(rB + j * 16 * 32);
#pragma unroll
        for (int i = 0; i < 4; ++i)
#pragma unroll
            for (int j = 0; j < 3; ++j)
                acc[i][j] = __builtin_amdgcn_mfma_f32_16x16x32_bf16(
                                af[i], bfr[j], acc[i][j], 0, 0, 0);
    }

    // two-phase epilogue over row halves; ep aliases staging (dead after sync)
    const int srow = tid >> 2;          // 0..63  (spline row within half)
    const int sg   = tid & 3;           // group within tile
#pragma unroll
    for (int e = 0; e < 2; ++e) {
        __syncthreads();                // staging/ep consumers done
        if (wm == (e << 6)) {           // waves holding rows [64e, 64e+64)
#pragma unroll
            for (int j = 0; j < 3; ++j) {
                const int col = wn + j * 16 + lrow;
                const float bv = bias[bn + col];
#pragma unroll
                for (int i = 0; i < 4; ++i) {
                    const int r0 = i * 16 + (lquad << 2);   // local row
#pragma unroll
                    for (int r = 0; r < 4; ++r)
                        ep[(r0 + r) * 97 + col] = acc[i][j][r] + bv;
                }
            }
        }
        __syncthreads();

        const int grow = bm + (e << 6) + srow;     // global batch row
        const float xv = x[(size_t)grow * N_IN + (4 * nt + sg)];
        float yv, ld;
        spline_eval(ep + srow * 97 + sg * OUT_PAD, xv, yv, ld);
        y[(size_t)grow * N_IN + 4 * nt + sg] = yv;

        // sum ld over the 4 lanes of the quad (same row)
        ld += __shfl_xor(ld, 1, 64);
        ld += __shfl_xor(ld, 2, 64);
        if (sg == 0) atomicAdd(&ldsum[grow], ld);
    }
}

// ---------------- host orchestration ----------------------------------------

extern "C" void kernel_launch(void* const* d_in, const int* in_sizes, int n_in,
                              void* d_out, int out_size, void* d_ws, size_t ws_size,
                              hipStream_t stream)
{
    const float* x     = (const float*)d_in[0];
    const float* ctx   = (const float*)d_in[1];
    const float* ctx_w = (const float*)d_in[2];
    const float* w0    = (const float*)d_in[3];
    const float* b0    = (const float*)d_in[4];
    const float* w1    = (const float*)d_in[5];
    const float* b1    = (const float*)d_in[6];
    const float* w2    = (const float*)d_in[7];
    const float* b2    = (const float*)d_in[8];
    // d_in[9..11] = masks: unused (computed analytically from indices)

    char* ws = (char*)d_ws;
    const size_t XCAT_B = (size_t)BATCH * KCAT * 2;   //   8 MB
    const size_t H_B    = (size_t)BATCH * HDIM * 2;   //  32 MB each
    const size_t WCAT_B = (size_t)HDIM * KCAT * 2;
    const size_t W1_B   = (size_t)HDIM * HDIM * 2;
    const size_t W2P_B  = (size_t)NOUTP * HDIM * 2;

    uint16_t* xcat = (uint16_t*)(ws);
    uint16_t* h1   = (uint16_t*)(ws + XCAT_B);
    uint16_t* h2   = (uint16_t*)(ws + XCAT_B + H_B);
    uint16_t* wcat = (uint16_t*)(ws + XCAT_B + 2 * H_B);
    uint16_t* w1m  = (uint16_t*)(ws + XCAT_B + 2 * H_B + WCAT_B);
    uint16_t* w2p  = (uint16_t*)(ws + XCAT_B + 2 * H_B + WCAT_B + W1_B);
    float*    b0p  = (float*)   (ws + XCAT_B + 2 * H_B + WCAT_B + W1_B + W2P_B);
    float*    b1p  = b0p + HDIM;
    float*    b2p  = b1p + HDIM;

    float* yout  = (float*)d_out;
    float* ldout = yout + (size_t)BATCH * N_IN;

    pack_all<<<33872, 256, 0, stream>>>(x, ctx, ctx_w, w0, b0, w1, b1, w2, b2,
                                        xcat, wcat, w1m, w2p, b0p, b1p, b2p,
                                        ldout);

    const dim3 blk(256);
    gemm_bt<0><<<dim3(128 * (HDIM / 128)), blk, 0, stream>>>(
        xcat, wcat, b0p, h1, HDIM, KCAT, HDIM / 128);
    gemm_bt<1><<<dim3(128 * (HDIM / 128)), blk, 0, stream>>>(
        h1, w1m, b1p, h2, HDIM, HDIM, HDIM / 128);
    gemm3_spline<<<dim3(128 * 32), blk, 0, stream>>>(
        h2, w2p, b2p, x, yout, ldout);
}

// Round 6
// 241.125 us; speedup vs baseline: 1.6059x; 1.0283x over previous
//
#include <hip/hip_runtime.h>
#include <cstdint>
#include <cstddef>

#define BATCH   16384
#define N_IN    128
#define CTX     128
#define HDIM    1024
#define NB      8
#define OUT_MULT 23                 // 3*NB-1 (logical)
#define OUT_PAD 24                  // padded per-group width (col 23 = zeros)
#define NOUTP   (N_IN * OUT_PAD)    // 3072
#define KCAT    (CTX + N_IN)        // 256

typedef __bf16 bf16x8 __attribute__((ext_vector_type(8)));
typedef float  f32x4  __attribute__((ext_vector_type(4)));

__device__ __forceinline__ uint16_t f2bf(float f) {
    union { float f; uint32_t u; } v; v.f = f;
    uint32_t u = v.u;
    u += 0x7FFFu + ((u >> 16) & 1u);   // RNE
    return (uint16_t)(u >> 16);
}

// ---- degree-sorted permutation of the hidden dim ---------------------------
// deg(h) = h % 127; stable sort by deg. count(d) = 9 for d<8, 8 for d>=8.
// kpref(d) = #{h : deg(h) < d}; position p -> (d, occurrence j) -> h = d+127*j
__device__ __forceinline__ int kpref_dev(int d) {
    return (d <= 8) ? 9 * d : 72 + 8 * (d - 8);
}
__device__ __forceinline__ int dpos_dev(int p) {
    return (p < 72) ? (p / 9) : (8 + ((p - 72) >> 3));
}
__device__ __forceinline__ int h_of(int p) {
    if (p < 72) { int d = p / 9, j = p - 9 * d; return d + 127 * j; }
    int q = p - 72; int d = 8 + (q >> 3); int j = q & 7; return d + 127 * j;
}

// async global->LDS, 16B per lane; LDS dest = wave-uniform base + lane*16,
// global side is a per-lane address (gather is allowed).
__device__ __forceinline__ void async_ld16(const void* g, const void* l) {
    __builtin_amdgcn_global_load_lds(
        (__attribute__((address_space(1))) void*)(uintptr_t)g,
        (__attribute__((address_space(3))) void*)(uint32_t)(uintptr_t)l,
        16, 0, 0);
}

// ---------------- one fused pack kernel (masks analytic, degree-sorted) -----
// block ranges: [0,16384) xcat | [16384,17408) wcat | [17408,21504) w1
//               [21504,33792) w2p | [33792,33808) biases | [33808,33872) ld=0

__global__ void pack_all(
    const float* __restrict__ x,    const float* __restrict__ ctx,
    const float* __restrict__ ctx_w,const float* __restrict__ w0,
    const float* __restrict__ b0,   const float* __restrict__ w1,
    const float* __restrict__ b1,   const float* __restrict__ w2,
    const float* __restrict__ b2,
    uint16_t* __restrict__ xcat, uint16_t* __restrict__ wcat,
    uint16_t* __restrict__ w1m,  uint16_t* __restrict__ w2p,
    float* __restrict__ b0p, float* __restrict__ b1p, float* __restrict__ b2p,
    float* __restrict__ ldz)
{
    const int blk = blockIdx.x;
    const int tid = threadIdx.x;
    if (blk < 16384) {                       // xcat: BATCH x KCAT
        int idx = blk * 256 + tid;
        int b = idx >> 8, c = idx & 255;
        float v = (c < CTX) ? ctx[(b << 7) + c] : x[(b << 7) + (c - CTX)];
        xcat[idx] = f2bf(v);
    } else if (blk < 17408) {                // wcat: HDIM x KCAT, rows sorted
        int idx = (blk - 16384) * 256 + tid;
        int p = idx >> 8, c = idx & 255;
        int h = h_of(p);
        float v;
        if (c < CTX) v = ctx_w[(h << 7) + c];
        else {
            int col = c - CTX;               // mask0: dpos(p) >= col
            v = (dpos_dev(p) >= col) ? w0[(h << 7) + col] : 0.0f;
        }
        wcat[idx] = f2bf(v);
    } else if (blk < 21504) {                // w1: HDIM x HDIM, both sorted
        int idx = (blk - 17408) * 256 + tid;
        int po = idx >> 10, pi = idx & 1023;
        float v = (dpos_dev(po) >= dpos_dev(pi))
                ? w1[h_of(po) * HDIM + h_of(pi)] : 0.0f;
        w1m[idx] = f2bf(v);
    } else if (blk < 33792) {                // w2p: NOUTP x HDIM, K sorted, padded
        int idx = (blk - 21504) * 256 + tid;
        int oo = idx >> 10, pi = idx & 1023;
        int g = oo / OUT_PAD, t = oo - g * OUT_PAD;
        float v = (t < OUT_MULT && g > dpos_dev(pi))
                ? w2[(g * OUT_MULT + t) * HDIM + h_of(pi)] : 0.0f;
        w2p[idx] = f2bf(v);
    } else if (blk < 33808) {                // biases
        int idx = (blk - 33792) * 256 + tid; // 0..4095
        if (idx < HDIM) {
            int h = h_of(idx);
            b0p[idx] = b0[h];
            b1p[idx] = b1[h];
        } else {
            int oo = idx - HDIM;             // 0..3071
            int g = oo / OUT_PAD, t = oo - g * OUT_PAD;
            b2p[oo] = (t < OUT_MULT) ? b2[g * OUT_MULT + t] : 0.0f;
        }
    } else {                                 // zero ldsum (BATCH floats)
        int idx = (blk - 33808) * 256 + tid;
        ldz[idx] = 0.0f;
    }
}

// ---------------- bf16 GEMM, C = A(MxK) @ B(NxK)^T + bias (relu, bf16 out) --
// BK=64 (2 MFMA substeps per barrier pair). LDS layout: row-major stride
// 64 elem (128 B), with octet XOR swizzle: chunk (row, j) holds global
// k-octet j^(row&7). Quarter-wave ds_read_b128 start banks 4*(o^(lrow&7))
// cover {0,4,...,28} exactly 2x -> conflict-free. Global side stays
// 128B-window coalesced (permutation within the row's 8 octets).
// MODE K prefix: 0: GEMM1 K_eff=128+dmax+1; 1: GEMM2 K_eff=kpref(dmax+1).

template<int MODE>
__global__ __launch_bounds__(256, 2) void gemm_bt(
    const uint16_t* __restrict__ A,
    const uint16_t* __restrict__ B,
    const float*    __restrict__ bias,
    uint16_t*       __restrict__ C,
    int N, int K, int NT)
{
    __shared__ __align__(16) uint16_t sA[128 * 64];   // 16 KB
    __shared__ __align__(16) uint16_t sB[128 * 64];   // 16 KB

    const int GM    = 64;
    const int per   = GM * NT;
    const int id    = blockIdx.x;
    const int grp   = id / per;
    const int rem   = id - grp * per;
    const int mt    = grp * GM + (rem & (GM - 1));
    const int nt    = rem >> 6;
    const int bm    = mt << 7;
    const int bn    = nt << 7;

    int K_eff;
    if (MODE == 0)      { int dmax = dpos_dev(bn + 127); K_eff = 128 + dmax + 1; }
    else                { int dmax = dpos_dev(bn + 127); K_eff = kpref_dev(dmax + 1); }
    K_eff = min(K, (K_eff + 63) & ~63);

    const int tid   = threadIdx.x;
    const int wid   = tid >> 6;
    const int lane  = tid & 63;
    const int wm    = (wid & 1) << 6;
    const int wn    = (wid >> 1) << 6;
    const int lrow  = lane & 15;
    const int lquad = lane >> 4;

    const f32x4 vzero = {0.0f, 0.0f, 0.0f, 0.0f};
    f32x4 acc[4][4];
#pragma unroll
    for (int i = 0; i < 4; ++i)
#pragma unroll
        for (int j = 0; j < 4; ++j) acc[i][j] = vzero;

    // staging: 1024 chunks each (A,B) per 64-K tile; 4 calls x 256 threads.
    int goff[4];
#pragma unroll
    for (int t = 0; t < 4; ++t) {
        int c = t * 256 + tid;
        int row = c >> 3, j = c & 7;
        int oct = j ^ (row & 7);
        goff[t] = row * K * 2 + oct * 16;    // bytes
    }
    const char* gA = (const char*)(A + (size_t)bm * K);
    const char* gB = (const char*)(B + (size_t)bn * K);

    const int octx = lrow & 7;
    const uint16_t* rA = sA + (wm + lrow) * 64;
    const uint16_t* rB = sB + (wn + lrow) * 64;

    for (int k0 = 0; k0 < K_eff; k0 += 64) {
        __syncthreads();
        const int kb = k0 * 2;
#pragma unroll
        for (int t = 0; t < 4; ++t) {
            const int ldsoff = (t * 256 + (wid << 6)) * 16;   // wave-uniform
            async_ld16(gA + goff[t] + kb, (const char*)sA + ldsoff);
            async_ld16(gB + goff[t] + kb, (const char*)sB + ldsoff);
        }
        __syncthreads();

#pragma unroll
        for (int ks = 0; ks < 2; ++ks) {
            const int oct = ((ks << 2) | lquad) ^ octx;
            bf16x8 af[4], bfr[4];
#pragma unroll
            for (int i = 0; i < 4; ++i) af[i]  = *(const bf16x8*)(rA + i * 1024 + oct * 8);
#pragma unroll
            for (int j = 0; j < 4; ++j) bfr[j] = *(const bf16x8*)(rB + j * 1024 + oct * 8);
#pragma unroll
            for (int i = 0; i < 4; ++i)
#pragma unroll
                for (int j = 0; j < 4; ++j)
                    acc[i][j] = __builtin_amdgcn_mfma_f32_16x16x32_bf16(
                                    af[i], bfr[j], acc[i][j], 0, 0, 0);
        }
    }

#pragma unroll
    for (int j = 0; j < 4; ++j) {
        const int col = bn + wn + j * 16 + lrow;
        const float bv = bias[col];
#pragma unroll
        for (int i = 0; i < 4; ++i) {
            const int row0 = bm + wm + i * 16 + (lquad << 2);
#pragma unroll
            for (int r = 0; r < 4; ++r) {
                float v = fmaxf(acc[i][j][r] + bv, 0.0f);
                C[(size_t)(row0 + r) * N + col] = f2bf(v);
            }
        }
    }
}

// ---------------- spline evaluation (f32 params, HW transcendentals) --------

__device__ __forceinline__ float frcp(float v) { return __builtin_amdgcn_rcpf(v); }
__device__ __forceinline__ float softplusf(float v) {
    return fmaxf(v, 0.0f) + __logf(1.0f + __expf(-fabsf(v)));
}

__device__ __forceinline__ void spline_eval(const float* __restrict__ pp,
                                            float xv, float& yout, float& ldout)
{
    float p[OUT_MULT];
#pragma unroll
    for (int k = 0; k < OUT_MULT; ++k) p[k] = pp[k];

    const float TAILF = 3.0f;
    const float MIN_W = 0.001f, MIN_H = 0.001f, MIN_D = 0.001f;
    const float INV_SCALE = 1.0f / 724.0773439350246f;   // 1/sqrt(H*H/2)

    const float xc = fminf(fmaxf(xv, -TAILF), TAILF);

    float uw[NB], uh[NB];
#pragma unroll
    for (int k = 0; k < NB; ++k) { uw[k] = p[k] * INV_SCALE; uh[k] = p[NB + k] * INV_SCALE; }
    float mw = uw[0], mh = uh[0];
#pragma unroll
    for (int k = 1; k < NB; ++k) { mw = fmaxf(mw, uw[k]); mh = fmaxf(mh, uh[k]); }
    float ew[NB], eh[NB], sw = 0.0f, sh = 0.0f;
#pragma unroll
    for (int k = 0; k < NB; ++k) {
        ew[k] = __expf(uw[k] - mw); sw += ew[k];
        eh[k] = __expf(uh[k] - mh); sh += eh[k];
    }
    const float FACW = (1.0f - MIN_W * NB) * frcp(sw);
    const float FACH = (1.0f - MIN_H * NB) * frcp(sh);

    float cw[NB + 1], ch[NB + 1];
    cw[0] = -TAILF; ch[0] = -TAILF;
    float aw = 0.0f, ah = 0.0f;
#pragma unroll
    for (int k = 0; k < NB; ++k) {
        aw += MIN_W + FACW * ew[k];
        ah += MIN_H + FACH * eh[k];
        cw[k + 1] = (k == NB - 1) ? TAILF : 2.0f * TAILF * aw - TAILF;
        ch[k + 1] = (k == NB - 1) ? TAILF : 2.0f * TAILF * ah - TAILF;
    }

    float dd[NB + 1];
    dd[0]  = 1.0f;   // MIN_D + softplus(DPAD) == 1 exactly by construction
    dd[NB] = 1.0f;
#pragma unroll
    for (int k = 1; k < NB; ++k) dd[k] = MIN_D + softplusf(p[2 * NB + (k - 1)]);

    float in_cw = cw[0], cw_n = cw[1], in_ch = ch[0], ch_n = ch[1];
    float d0 = dd[0], d1 = dd[1];
#pragma unroll
    for (int k = 1; k < NB; ++k) {
        const bool ge = (xc >= cw[k]);
        in_cw = ge ? cw[k]     : in_cw;
        cw_n  = ge ? cw[k + 1] : cw_n;
        in_ch = ge ? ch[k]     : in_ch;
        ch_n  = ge ? ch[k + 1] : ch_n;
        d0    = ge ? dd[k]     : d0;
        d1    = ge ? dd[k + 1] : d1;
    }
    const float in_w  = cw_n - in_cw;
    const float in_h  = ch_n - in_ch;
    const float inv_w = frcp(in_w);
    const float delta = in_h * inv_w;
    const float theta = (xc - in_cw) * inv_w;
    const float omt   = 1.0f - theta;
    const float t1m   = theta * omt;
    const float denom = delta + (d0 + d1 - 2.0f * delta) * t1m;
    const float num   = in_h * (delta * theta * theta + d0 * t1m);
    float yv = in_ch + num * frcp(denom);
    float ld = 2.0f * __logf(delta)
             + __logf(d1 * theta * theta + 2.0f * delta * t1m + d0 * omt * omt)
             - 2.0f * __logf(denom);
    const bool inside = fabsf(xv) <= TAILF;
    yout  = inside ? yv : xv;
    ldout = inside ? ld : 0.0f;
}

// ---------------- fused GEMM3 + spline --------------------------------------
// Block tile: 128 M x 96 N (= 4 complete padded groups). Waves 2x2: 64 x 48.
// BK=64 + XOR-swizzled LDS (see gemm_bt). K prefix: kpref(4*nt+3) rounded
// to 64 (extra K reads hit exactly-zero B rows -> bit-identical).
// Two-phase spline epilogue through a 64x97 f32 LDS tile aliasing the dead
// staging buffers (LDS block = 28.7 KB).

__global__ __launch_bounds__(256, 2) void gemm3_spline(
    const uint16_t* __restrict__ A,      // h2: BATCH x HDIM (sorted K)
    const uint16_t* __restrict__ B,      // w2p: NOUTP x HDIM
    const float*    __restrict__ bias,   // b2p: NOUTP
    const float*    __restrict__ x,      // BATCH x N_IN
    float* __restrict__ y,
    float* __restrict__ ldsum)
{
    __shared__ __align__(16) char smem[128 * 64 * 2 + 96 * 64 * 2];  // 28672 B
    uint16_t* sA = (uint16_t*)smem;                 // 128*64*2 = 16384
    uint16_t* sB = (uint16_t*)(smem + 16384);       //  96*64*2 = 12288
    float* ep    = (float*)smem;                    // 64*97*4 = 24832 (alias)

    const int NT  = 32;
    const int per = 64 * NT;                        // 2048
    const int id  = blockIdx.x;
    const int grp = id / per;
    const int rem = id - grp * per;
    const int mt  = grp * 64 + (rem & 63);
    const int nt  = rem >> 6;
    const int bm  = mt << 7;
    const int bn  = nt * 96;

    const int K = HDIM;
    int K_eff = kpref_dev(4 * nt + 3);
    K_eff = min(K, (K_eff + 63) & ~63);

    const int tid   = threadIdx.x;
    const int wid   = tid >> 6;
    const int lane  = tid & 63;
    const int wm    = (wid & 1) << 6;
    const int wn    = (wid >> 1) * 48;
    const int lrow  = lane & 15;
    const int lquad = lane >> 4;

    const f32x4 vzero = {0.0f, 0.0f, 0.0f, 0.0f};
    f32x4 acc[4][3];
#pragma unroll
    for (int i = 0; i < 4; ++i)
#pragma unroll
        for (int j = 0; j < 3; ++j) acc[i][j] = vzero;

    // A: 1024 chunks (4 calls); B: 768 chunks (3 calls)
    int goffA[4], goffB[3];
#pragma unroll
    for (int t = 0; t < 4; ++t) {
        int c = t * 256 + tid;
        int row = c >> 3, j = c & 7;
        goffA[t] = row * K * 2 + (j ^ (row & 7)) * 16;
    }
#pragma unroll
    for (int t = 0; t < 3; ++t) {
        int c = t * 256 + tid;
        int row = c >> 3, j = c & 7;
        goffB[t] = row * K * 2 + (j ^ (row & 7)) * 16;
    }
    const char* gA = (const char*)(A + (size_t)bm * K);
    const char* gB = (const char*)(B + (size_t)bn * K);

    const int octx = lrow & 7;
    const uint16_t* rA = sA + (wm + lrow) * 64;
    const uint16_t* rB = sB + (wn + lrow) * 64;

    for (int k0 = 0; k0 < K_eff; k0 += 64) {
        __syncthreads();
        const int kb = k0 * 2;
#pragma unroll
        for (int t = 0; t < 4; ++t) {
            const int ldsoff = (t * 256 + (wid << 6)) * 16;
            async_ld16(gA + goffA[t] + kb, (const char*)sA + ldsoff);
            if (t < 3)
                async_ld16(gB + goffB[t] + kb, (const char*)sB + ldsoff);
        }
        __syncthreads();

#pragma unroll
        for (int ks = 0; ks < 2; ++ks) {
            const int oct = ((ks << 2) | lquad) ^ octx;
            bf16x8 af[4], bfr[3];
#pragma unroll
            for (int i = 0; i < 4; ++i) af[i]  = *(const bf16x8*)(rA + i * 1024 + oct * 8);
#pragma unroll
            for (int j = 0; j < 3; ++j) bfr[j] = *(const bf16x8*)(rB + j * 1024 + oct * 8);
#pragma unroll
            for (int i = 0; i < 4; ++i)
#pragma unroll
                for (int j = 0; j < 3; ++j)
                    acc[i][j] = __builtin_amdgcn_mfma_f32_16x16x32_bf16(
                                    af[i], bfr[j], acc[i][j], 0, 0, 0);
        }
    }

    // two-phase epilogue over row halves; ep aliases staging (dead after sync)
    const int srow = tid >> 2;          // 0..63  (spline row within half)
    const int sg   = tid & 3;           // group within tile
#pragma unroll
    for (int e = 0; e < 2; ++e) {
        __syncthreads();                // staging/ep consumers done
        if (wm == (e << 6)) {           // waves holding rows [64e, 64e+64)
#pragma unroll
            for (int j = 0; j < 3; ++j) {
                const int col = wn + j * 16 + lrow;
                const float bv = bias[bn + col];
#pragma unroll
                for (int i = 0; i < 4; ++i) {
                    const int r0 = i * 16 + (lquad << 2);   // local row
#pragma unroll
                    for (int r = 0; r < 4; ++r)
                        ep[(r0 + r) * 97 + col] = acc[i][j][r] + bv;
                }
            }
        }
        __syncthreads();

        const int grow = bm + (e << 6) + srow;     // global batch row
        const float xv = x[(size_t)grow * N_IN + (4 * nt + sg)];
        float yv, ld;
        spline_eval(ep + srow * 97 + sg * OUT_PAD, xv, yv, ld);
        y[(size_t)grow * N_IN + 4 * nt + sg] = yv;

        // sum ld over the 4 lanes of the quad (same row)
        ld += __shfl_xor(ld, 1, 64);
        ld += __shfl_xor(ld, 2, 64);
        if (sg == 0) atomicAdd(&ldsum[grow], ld);
    }
}

// ---------------- host orchestration ----------------------------------------

extern "C" void kernel_launch(void* const* d_in, const int* in_sizes, int n_in,
                              void* d_out, int out_size, void* d_ws, size_t ws_size,
                              hipStream_t stream)
{
    const float* x     = (const float*)d_in[0];
    const float* ctx   = (const float*)d_in[1];
    const float* ctx_w = (const float*)d_in[2];
    const float* w0    = (const float*)d_in[3];
    const float* b0    = (const float*)d_in[4];
    const float* w1    = (const float*)d_in[5];
    const float* b1    = (const float*)d_in[6];
    const float* w2    = (const float*)d_in[7];
    const float* b2    = (const float*)d_in[8];
    // d_in[9..11] = masks: unused (computed analytically from indices)

    char* ws = (char*)d_ws;
    const size_t XCAT_B = (size_t)BATCH * KCAT * 2;   //   8 MB
    const size_t H_B    = (size_t)BATCH * HDIM * 2;   //  32 MB each
    const size_t WCAT_B = (size_t)HDIM * KCAT * 2;
    const size_t W1_B   = (size_t)HDIM * HDIM * 2;
    const size_t W2P_B  = (size_t)NOUTP * HDIM * 2;

    uint16_t* xcat = (uint16_t*)(ws);
    uint16_t* h1   = (uint16_t*)(ws + XCAT_B);
    uint16_t* h2   = (uint16_t*)(ws + XCAT_B + H_B);
    uint16_t* wcat = (uint16_t*)(ws + XCAT_B + 2 * H_B);
    uint16_t* w1m  = (uint16_t*)(ws + XCAT_B + 2 * H_B + WCAT_B);
    uint16_t* w2p  = (uint16_t*)(ws + XCAT_B + 2 * H_B + WCAT_B + W1_B);
    float*    b0p  = (float*)   (ws + XCAT_B + 2 * H_B + WCAT_B + W1_B + W2P_B);
    float*    b1p  = b0p + HDIM;
    float*    b2p  = b1p + HDIM;

    float* yout  = (float*)d_out;
    float* ldout = yout + (size_t)BATCH * N_IN;

    pack_all<<<33872, 256, 0, stream>>>(x, ctx, ctx_w, w0, b0, w1, b1, w2, b2,
                                        xcat, wcat, w1m, w2p, b0p, b1p, b2p,
                                        ldout);

    const dim3 blk(256);
    gemm_bt<0><<<dim3(128 * (HDIM / 128)), blk, 0, stream>>>(
        xcat, wcat, b0p, h1, HDIM, KCAT, HDIM / 128);
    gemm_bt<1><<<dim3(128 * (HDIM / 128)), blk, 0, stream>>>(
        h1, w1m, b1p, h2, HDIM, HDIM, HDIM / 128);
    gemm3_spline<<<dim3(128 * 32), blk, 0, stream>>>(
        h2, w2p, b2p, x, yout, ldout);
}

// Round 9
// 220.657 us; speedup vs baseline: 1.7549x; 1.0928x over previous
//
#include <hip/hip_runtime.h>
#include <cstdint>
#include <cstddef>

#define BATCH   16384
#define N_IN    128
#define CTX     128
#define HDIM    1024
#define NB      8
#define OUT_MULT 23                 // 3*NB-1 (logical)
#define OUT_PAD 24                  // padded per-group width (col 23 = zeros)
#define NOUTP   (N_IN * OUT_PAD)    // 3072
#define KCAT    (CTX + N_IN)        // 256

typedef __bf16 bf16x8 __attribute__((ext_vector_type(8)));
typedef float  f32x4  __attribute__((ext_vector_type(4)));

__device__ __forceinline__ uint16_t f2bf(float f) {
    union { float f; uint32_t u; } v; v.f = f;
    uint32_t u = v.u;
    u += 0x7FFFu + ((u >> 16) & 1u);   // RNE
    return (uint16_t)(u >> 16);
}

// ---- degree-sorted permutation of the hidden dim ---------------------------
// deg(h) = h % 127; stable sort by deg. count(d) = 9 for d<8, 8 for d>=8.
// kpref(d) = #{h : deg(h) < d}; position p -> (d, occurrence j) -> h = d+127*j
__device__ __forceinline__ int kpref_dev(int d) {
    return (d <= 8) ? 9 * d : 72 + 8 * (d - 8);
}
__device__ __forceinline__ int dpos_dev(int p) {
    return (p < 72) ? (p / 9) : (8 + ((p - 72) >> 3));
}
__device__ __forceinline__ int h_of(int p) {
    if (p < 72) { int d = p / 9, j = p - 9 * d; return d + 127 * j; }
    int q = p - 72; int d = 8 + (q >> 3); int j = q & 7; return d + 127 * j;
}

// async global->LDS, 16B per lane; LDS dest = wave-uniform base + lane*16,
// global side is a per-lane address (gather is allowed).
__device__ __forceinline__ void async_ld16(const void* g, const void* l) {
    __builtin_amdgcn_global_load_lds(
        (__attribute__((address_space(1))) void*)(uintptr_t)g,
        (__attribute__((address_space(3))) void*)(uint32_t)(uintptr_t)l,
        16, 0, 0);
}

// ---------------- one fused pack kernel (coalesced; exonerated by bisection) -
// All reads AND writes coalesced; column permutation done via an LDS-staged
// source row (gathers from LDS are cheap, global stays streaming).
// block ranges: [0,4096) xcat | [4096,5120) wcat | [5120,6144) w1m
//               [6144,9216) w2p | [9216,9232) biases | [9232,9296) ld=0

__global__ void pack_all(
    const float* __restrict__ x,    const float* __restrict__ ctx,
    const float* __restrict__ ctx_w,const float* __restrict__ w0,
    const float* __restrict__ b0,   const float* __restrict__ w1,
    const float* __restrict__ b1,   const float* __restrict__ w2,
    const float* __restrict__ b2,
    uint16_t* __restrict__ xcat, uint16_t* __restrict__ wcat,
    uint16_t* __restrict__ w1m,  uint16_t* __restrict__ w2p,
    float* __restrict__ b0p, float* __restrict__ b1p, float* __restrict__ b2p,
    float* __restrict__ ldz)
{
    __shared__ float srow[HDIM];             // 4 KB staging for permuted packs
    const int blk = blockIdx.x;
    const int tid = threadIdx.x;

    if (blk < 4096) {                        // xcat: BATCH x KCAT, 4 elem/thread
        int idx4 = (blk * 256 + tid) * 4;
        int b = idx4 >> 8, c = idx4 & 255;
        f32x4 v = (c < CTX) ? *(const f32x4*)(ctx + (b << 7) + c)
                            : *(const f32x4*)(x   + (b << 7) + (c - CTX));
        ushort4 o;
        o.x = f2bf(v[0]); o.y = f2bf(v[1]); o.z = f2bf(v[2]); o.w = f2bf(v[3]);
        *(ushort4*)(xcat + idx4) = o;
    } else if (blk < 5120) {                 // wcat: HDIM x KCAT, rows sorted
        int idx = (blk - 4096) * 256 + tid;
        int p = idx >> 8, c = idx & 255;
        int h = h_of(p);
        float v;
        if (c < CTX) v = ctx_w[(h << 7) + c];
        else {
            int col = c - CTX;               // mask0: dpos(p) >= col
            v = (dpos_dev(p) >= col) ? w0[(h << 7) + col] : 0.0f;
        }
        wcat[idx] = f2bf(v);
    } else if (blk < 6144) {                 // w1m: one dest row per block
        const int po = blk - 5120;
        const int drow = dpos_dev(po);
        const float* src = w1 + (size_t)h_of(po) * HDIM;
        *((f32x4*)srow + tid) = *((const f32x4*)src + tid);   // 1024 floats
        __syncthreads();
        ushort4 o;
#pragma unroll
        for (int e = 0; e < 4; ++e) {
            int pi = 4 * tid + e;
            float v = (drow >= dpos_dev(pi)) ? srow[h_of(pi)] : 0.0f;
            ((uint16_t*)&o)[e] = f2bf(v);
        }
        *((ushort4*)(w1m + (size_t)po * HDIM) + tid) = o;
    } else if (blk < 9216) {                 // w2p: one dest row per block
        const int oo = blk - 6144;           // 0..3071
        const int g = oo / OUT_PAD, t = oo - g * OUT_PAD;
        const bool live = (t < OUT_MULT);    // block-uniform branch
        if (live) {
            const float* src = w2 + (size_t)(g * OUT_MULT + t) * HDIM;
            *((f32x4*)srow + tid) = *((const f32x4*)src + tid);
        }
        __syncthreads();
        ushort4 o;
#pragma unroll
        for (int e = 0; e < 4; ++e) {
            int pi = 4 * tid + e;
            float v = (live && g > dpos_dev(pi)) ? srow[h_of(pi)] : 0.0f;
            ((uint16_t*)&o)[e] = f2bf(v);
        }
        *((ushort4*)(w2p + (size_t)oo * HDIM) + tid) = o;
    } else if (blk < 9232) {                 // biases
        int idx = (blk - 9216) * 256 + tid;  // 0..4095
        if (idx < HDIM) {
            int h = h_of(idx);
            b0p[idx] = b0[h];
            b1p[idx] = b1[h];
        } else {
            int oo = idx - HDIM;             // 0..3071
            int g = oo / OUT_PAD, t = oo - g * OUT_PAD;
            b2p[oo] = (t < OUT_MULT) ? b2[g * OUT_MULT + t] : 0.0f;
        }
    } else {                                 // zero ldsum (BATCH floats)
        int idx = (blk - 9232) * 256 + tid;
        ldz[idx] = 0.0f;
    }
}

// ---------------- bf16 GEMM, C = A(MxK) @ B(NxK)^T + bias (relu, bf16 out) --
// BK=64, XOR-swizzled LDS (conflict-free ds_read_b128), K prefix by MODE.

template<int MODE>
__global__ __launch_bounds__(256, 2) void gemm_bt(
    const uint16_t* __restrict__ A,
    const uint16_t* __restrict__ B,
    const float*    __restrict__ bias,
    uint16_t*       __restrict__ C,
    int N, int K, int NT)
{
    __shared__ __align__(16) uint16_t sA[128 * 64];   // 16 KB
    __shared__ __align__(16) uint16_t sB[128 * 64];   // 16 KB

    const int GM    = 64;
    const int per   = GM * NT;
    const int id    = blockIdx.x;
    const int grp   = id / per;
    const int rem   = id - grp * per;
    const int mt    = grp * GM + (rem & (GM - 1));
    const int nt    = rem >> 6;
    const int bm    = mt << 7;
    const int bn    = nt << 7;

    int K_eff;
    if (MODE == 0)      { int dmax = dpos_dev(bn + 127); K_eff = 128 + dmax + 1; }
    else                { int dmax = dpos_dev(bn + 127); K_eff = kpref_dev(dmax + 1); }
    K_eff = min(K, (K_eff + 63) & ~63);

    const int tid   = threadIdx.x;
    const int wid   = tid >> 6;
    const int lane  = tid & 63;
    const int wm    = (wid & 1) << 6;
    const int wn    = (wid >> 1) << 6;
    const int lrow  = lane & 15;
    const int lquad = lane >> 4;

    const f32x4 vzero = {0.0f, 0.0f, 0.0f, 0.0f};
    f32x4 acc[4][4];
#pragma unroll
    for (int i = 0; i < 4; ++i)
#pragma unroll
        for (int j = 0; j < 4; ++j) acc[i][j] = vzero;

    int goff[4];
#pragma unroll
    for (int t = 0; t < 4; ++t) {
        int c = t * 256 + tid;
        int row = c >> 3, j = c & 7;
        int oct = j ^ (row & 7);
        goff[t] = row * K * 2 + oct * 16;    // bytes
    }
    const char* gA = (const char*)(A + (size_t)bm * K);
    const char* gB = (const char*)(B + (size_t)bn * K);

    const int octx = lrow & 7;
    const uint16_t* rA = sA + (wm + lrow) * 64;
    const uint16_t* rB = sB + (wn + lrow) * 64;

    for (int k0 = 0; k0 < K_eff; k0 += 64) {
        __syncthreads();
        const int kb = k0 * 2;
#pragma unroll
        for (int t = 0; t < 4; ++t) {
            const int ldsoff = (t * 256 + (wid << 6)) * 16;   // wave-uniform
            async_ld16(gA + goff[t] + kb, (const char*)sA + ldsoff);
            async_ld16(gB + goff[t] + kb, (const char*)sB + ldsoff);
        }
        __syncthreads();

#pragma unroll
        for (int ks = 0; ks < 2; ++ks) {
            const int oct = ((ks << 2) | lquad) ^ octx;
            bf16x8 af[4], bfr[4];
#pragma unroll
            for (int i = 0; i < 4; ++i) af[i]  = *(const bf16x8*)(rA + i * 1024 + oct * 8);
#pragma unroll
            for (int j = 0; j < 4; ++j) bfr[j] = *(const bf16x8*)(rB + j * 1024 + oct * 8);
#pragma unroll
            for (int i = 0; i < 4; ++i)
#pragma unroll
                for (int j = 0; j < 4; ++j)
                    acc[i][j] = __builtin_amdgcn_mfma_f32_16x16x32_bf16(
                                    af[i], bfr[j], acc[i][j], 0, 0, 0);
        }
    }

#pragma unroll
    for (int j = 0; j < 4; ++j) {
        const int col = bn + wn + j * 16 + lrow;
        const float bv = bias[col];
#pragma unroll
        for (int i = 0; i < 4; ++i) {
            const int row0 = bm + wm + i * 16 + (lquad << 2);
#pragma unroll
            for (int r = 0; r < 4; ++r) {
                float v = fmaxf(acc[i][j][r] + bv, 0.0f);
                C[(size_t)(row0 + r) * N + col] = f2bf(v);
            }
        }
    }
}

// ---------------- spline evaluation (ROUND-6 VERBATIM, known good) ----------
// NOTE: the trans-op diet (Taylor softmax exp + fused log) failed absmax=0.75
// in R7/R8 despite airtight algebra -- unresolved, suspect miscompile of the
// 16x-inlined polynomial. Do NOT re-apply without disasm-level isolation.

__device__ __forceinline__ float frcp(float v) { return __builtin_amdgcn_rcpf(v); }
__device__ __forceinline__ float softplusf(float v) {
    return fmaxf(v, 0.0f) + __logf(1.0f + __expf(-fabsf(v)));
}

__device__ __forceinline__ void spline_eval(const float* __restrict__ pp,
                                            float xv, float& yout, float& ldout)
{
    float p[OUT_MULT];
#pragma unroll
    for (int k = 0; k < OUT_MULT; ++k) p[k] = pp[k];

    const float TAILF = 3.0f;
    const float MIN_W = 0.001f, MIN_H = 0.001f, MIN_D = 0.001f;
    const float INV_SCALE = 1.0f / 724.0773439350246f;   // 1/sqrt(H*H/2)

    const float xc = fminf(fmaxf(xv, -TAILF), TAILF);

    float uw[NB], uh[NB];
#pragma unroll
    for (int k = 0; k < NB; ++k) { uw[k] = p[k] * INV_SCALE; uh[k] = p[NB + k] * INV_SCALE; }
    float mw = uw[0], mh = uh[0];
#pragma unroll
    for (int k = 1; k < NB; ++k) { mw = fmaxf(mw, uw[k]); mh = fmaxf(mh, uh[k]); }
    float ew[NB], eh[NB], sw = 0.0f, sh = 0.0f;
#pragma unroll
    for (int k = 0; k < NB; ++k) {
        ew[k] = __expf(uw[k] - mw); sw += ew[k];
        eh[k] = __expf(uh[k] - mh); sh += eh[k];
    }
    const float FACW = (1.0f - MIN_W * NB) * frcp(sw);
    const float FACH = (1.0f - MIN_H * NB) * frcp(sh);

    float cw[NB + 1], ch[NB + 1];
    cw[0] = -TAILF; ch[0] = -TAILF;
    float aw = 0.0f, ah = 0.0f;
#pragma unroll
    for (int k = 0; k < NB; ++k) {
        aw += MIN_W + FACW * ew[k];
        ah += MIN_H + FACH * eh[k];
        cw[k + 1] = (k == NB - 1) ? TAILF : 2.0f * TAILF * aw - TAILF;
        ch[k + 1] = (k == NB - 1) ? TAILF : 2.0f * TAILF * ah - TAILF;
    }

    float dd[NB + 1];
    dd[0]  = 1.0f;   // MIN_D + softplus(DPAD) == 1 exactly by construction
    dd[NB] = 1.0f;
#pragma unroll
    for (int k = 1; k < NB; ++k) dd[k] = MIN_D + softplusf(p[2 * NB + (k - 1)]);

    float in_cw = cw[0], cw_n = cw[1], in_ch = ch[0], ch_n = ch[1];
    float d0 = dd[0], d1 = dd[1];
#pragma unroll
    for (int k = 1; k < NB; ++k) {
        const bool ge = (xc >= cw[k]);
        in_cw = ge ? cw[k]     : in_cw;
        cw_n  = ge ? cw[k + 1] : cw_n;
        in_ch = ge ? ch[k]     : in_ch;
        ch_n  = ge ? ch[k + 1] : ch_n;
        d0    = ge ? dd[k]     : d0;
        d1    = ge ? dd[k + 1] : d1;
    }
    const float in_w  = cw_n - in_cw;
    const float in_h  = ch_n - in_ch;
    const float inv_w = frcp(in_w);
    const float delta = in_h * inv_w;
    const float theta = (xc - in_cw) * inv_w;
    const float omt   = 1.0f - theta;
    const float t1m   = theta * omt;
    const float denom = delta + (d0 + d1 - 2.0f * delta) * t1m;
    const float num   = in_h * (delta * theta * theta + d0 * t1m);
    float yv = in_ch + num * frcp(denom);
    float ld = 2.0f * __logf(delta)
             + __logf(d1 * theta * theta + 2.0f * delta * t1m + d0 * omt * omt)
             - 2.0f * __logf(denom);
    const bool inside = fabsf(xv) <= TAILF;
    yout  = inside ? yv : xv;
    ldout = inside ? ld : 0.0f;
}

// ---------------- fused GEMM3 + spline --------------------------------------
// Block tile: 128 M x 96 N (= 4 complete padded groups). Waves 2x2: 64 x 48.
// BK=64 + XOR-swizzled LDS. K prefix: kpref(4*nt+3) rounded to 64
// (zero-weight tail -> bit-identical). Two-phase spline epilogue through a
// 64x97 f32 LDS tile aliasing the dead staging buffers.

__global__ __launch_bounds__(256, 2) void gemm3_spline(
    const uint16_t* __restrict__ A,      // h2: BATCH x HDIM (sorted K)
    const uint16_t* __restrict__ B,      // w2p: NOUTP x HDIM
    const float*    __restrict__ bias,   // b2p: NOUTP
    const float*    __restrict__ x,      // BATCH x N_IN
    float* __restrict__ y,
    float* __restrict__ ldsum)
{
    __shared__ __align__(16) char smem[128 * 64 * 2 + 96 * 64 * 2];  // 28672 B
    uint16_t* sA = (uint16_t*)smem;                 // 128*64*2 = 16384
    uint16_t* sB = (uint16_t*)(smem + 16384);       //  96*64*2 = 12288
    float* ep    = (float*)smem;                    // 64*97*4 = 24832 (alias)

    const int NT  = 32;
    const int per = 64 * NT;                        // 2048
    const int id  = blockIdx.x;
    const int grp = id / per;
    const int rem = id - grp * per;
    const int mt  = grp * 64 + (rem & 63);
    const int nt  = rem >> 6;
    const int bm  = mt << 7;
    const int bn  = nt * 96;

    const int K = HDIM;
    int K_eff = kpref_dev(4 * nt + 3);
    K_eff = min(K, (K_eff + 63) & ~63);

    const int tid   = threadIdx.x;
    const int wid   = tid >> 6;
    const int lane  = tid & 63;
    const int wm    = (wid & 1) << 6;
    const int wn    = (wid >> 1) * 48;
    const int lrow  = lane & 15;
    const int lquad = lane >> 4;

    const f32x4 vzero = {0.0f, 0.0f, 0.0f, 0.0f};
    f32x4 acc[4][3];
#pragma unroll
    for (int i = 0; i < 4; ++i)
#pragma unroll
        for (int j = 0; j < 3; ++j) acc[i][j] = vzero;

    int goffA[4], goffB[3];
#pragma unroll
    for (int t = 0; t < 4; ++t) {
        int c = t * 256 + tid;
        int row = c >> 3, j = c & 7;
        goffA[t] = row * K * 2 + (j ^ (row & 7)) * 16;
    }
#pragma unroll
    for (int t = 0; t < 3; ++t) {
        int c = t * 256 + tid;
        int row = c >> 3, j = c & 7;
        goffB[t] = row * K * 2 + (j ^ (row & 7)) * 16;
    }
    const char* gA = (const char*)(A + (size_t)bm * K);
    const char* gB = (const char*)(B + (size_t)bn * K);

    const int octx = lrow & 7;
    const uint16_t* rA = sA + (wm + lrow) * 64;
    const uint16_t* rB = sB + (wn + lrow) * 64;

    for (int k0 = 0; k0 < K_eff; k0 += 64) {
        __syncthreads();
        const int kb = k0 * 2;
#pragma unroll
        for (int t = 0; t < 4; ++t) {
            const int ldsoff = (t * 256 + (wid << 6)) * 16;
            async_ld16(gA + goffA[t] + kb, (const char*)sA + ldsoff);
            if (t < 3)
                async_ld16(gB + goffB[t] + kb, (const char*)sB + ldsoff);
        }
        __syncthreads();

#pragma unroll
        for (int ks = 0; ks < 2; ++ks) {
            const int oct = ((ks << 2) | lquad) ^ octx;
            bf16x8 af[4], bfr[3];
#pragma unroll
            for (int i = 0; i < 4; ++i) af[i]  = *(const bf16x8*)(rA + i * 1024 + oct * 8);
#pragma unroll
            for (int j = 0; j < 3; ++j) bfr[j] = *(const bf16x8*)(rB + j * 1024 + oct * 8);
#pragma unroll
            for (int i = 0; i < 4; ++i)
#pragma unroll
                for (int j = 0; j < 3; ++j)
                    acc[i][j] = __builtin_amdgcn_mfma_f32_16x16x32_bf16(
                                    af[i], bfr[j], acc[i][j], 0, 0, 0);
        }
    }

    // two-phase epilogue over row halves; ep aliases staging (dead after sync)
    const int srow = tid >> 2;          // 0..63  (spline row within half)
    const int sg   = tid & 3;           // group within tile
#pragma unroll
    for (int e = 0; e < 2; ++e) {
        __syncthreads();                // staging/ep consumers done
        if (wm == (e << 6)) {           // waves holding rows [64e, 64e+64)
#pragma unroll
            for (int j = 0; j < 3; ++j) {
                const int col = wn + j * 16 + lrow;
                const float bv = bias[bn + col];
#pragma unroll
                for (int i = 0; i < 4; ++i) {
                    const int r0 = i * 16 + (lquad << 2);   // local row
#pragma unroll
                    for (int r = 0; r < 4; ++r)
                        ep[(r0 + r) * 97 + col] = acc[i][j][r] + bv;
                }
            }
        }
        __syncthreads();

        const int grow = bm + (e << 6) + srow;     // global batch row
        const float xv = x[(size_t)grow * N_IN + (4 * nt + sg)];
        float yv, ld;
        spline_eval(ep + srow * 97 + sg * OUT_PAD, xv, yv, ld);
        y[(size_t)grow * N_IN + 4 * nt + sg] = yv;

        // sum ld over the 4 lanes of the quad (same row)
        ld += __shfl_xor(ld, 1, 64);
        ld += __shfl_xor(ld, 2, 64);
        if (sg == 0) atomicAdd(&ldsum[grow], ld);
    }
}

// ---------------- host orchestration ----------------------------------------

extern "C" void kernel_launch(void* const* d_in, const int* in_sizes, int n_in,
                              void* d_out, int out_size, void* d_ws, size_t ws_size,
                              hipStream_t stream)
{
    const float* x     = (const float*)d_in[0];
    const float* ctx   = (const float*)d_in[1];
    const float* ctx_w = (const float*)d_in[2];
    const float* w0    = (const float*)d_in[3];
    const float* b0    = (const float*)d_in[4];
    const float* w1    = (const float*)d_in[5];
    const float* b1    = (const float*)d_in[6];
    const float* w2    = (const float*)d_in[7];
    const float* b2    = (const float*)d_in[8];
    // d_in[9..11] = masks: unused (computed analytically from indices)

    char* ws = (char*)d_ws;
    const size_t XCAT_B = (size_t)BATCH * KCAT * 2;   //   8 MB
    const size_t H_B    = (size_t)BATCH * HDIM * 2;   //  32 MB each
    const size_t WCAT_B = (size_t)HDIM * KCAT * 2;
    const size_t W1_B   = (size_t)HDIM * HDIM * 2;
    const size_t W2P_B  = (size_t)NOUTP * HDIM * 2;

    uint16_t* xcat = (uint16_t*)(ws);
    uint16_t* h1   = (uint16_t*)(ws + XCAT_B);
    uint16_t* h2   = (uint16_t*)(ws + XCAT_B + H_B);
    uint16_t* wcat = (uint16_t*)(ws + XCAT_B + 2 * H_B);
    uint16_t* w1m  = (uint16_t*)(ws + XCAT_B + 2 * H_B + WCAT_B);
    uint16_t* w2p  = (uint16_t*)(ws + XCAT_B + 2 * H_B + WCAT_B + W1_B);
    float*    b0p  = (float*)   (ws + XCAT_B + 2 * H_B + WCAT_B + W1_B + W2P_B);
    float*    b1p  = b0p + HDIM;
    float*    b2p  = b1p + HDIM;

    float* yout  = (float*)d_out;
    float* ldout = yout + (size_t)BATCH * N_IN;

    pack_all<<<9296, 256, 0, stream>>>(x, ctx, ctx_w, w0, b0, w1, b1, w2, b2,
                                       xcat, wcat, w1m, w2p, b0p, b1p, b2p,
                                       ldout);

    const dim3 blk(256);
    gemm_bt<0><<<dim3(128 * (HDIM / 128)), blk, 0, stream>>>(
        xcat, wcat, b0p, h1, HDIM, KCAT, HDIM / 128);
    gemm_bt<1><<<dim3(128 * (HDIM / 128)), blk, 0, stream>>>(
        h1, w1m, b1p, h2, HDIM, HDIM, HDIM / 128);
    gemm3_spline<<<dim3(128 * 32), blk, 0, stream>>>(
        h2, w2p, b2p, x, yout, ldout);
}